// Round 5
// baseline (679.268 us; speedup 1.0000x reference)
//
#include <hip/hip_runtime.h>

// Problem constants
#define BB 32
#define NN 2048
#define FF 3
#define HH 64
#define OUTC 128
#define KK 16
#define BN (BB * NN)   // 65536 points

typedef __attribute__((ext_vector_type(8))) __bf16 bf16x8;
typedef __attribute__((ext_vector_type(4))) float f32x4;

// Pack d2 + candidate index into one sortable u32:
// high 21 bits = monotone(float d2) truncated, low 11 bits = idx (NN=2^11).
__device__ __forceinline__ unsigned int packkey(float d2, unsigned int m) {
    unsigned int bb = __builtin_bit_cast(unsigned int, d2);
    unsigned int msk = (unsigned int)((int)bb >> 31);
    unsigned int srt = bb ^ (msk | 0x80000000u);
    return (srt & 0xFFFFF800u) | m;
}

// Full-precision sortable key: 32-bit monotone(f32) << 11 | idx. Lexicographic
// (d2, j) order in a single u64 compare — exact, tie-break on smaller index.
__device__ __forceinline__ unsigned long long pack64(float d2, unsigned int j) {
    unsigned int bb = __builtin_bit_cast(unsigned int, d2);
    unsigned int msk = (unsigned int)((int)bb >> 31);
    unsigned int srt = bb ^ (msk | 0x80000000u);
    return ((unsigned long long)srt << 11) | j;
}

__device__ __forceinline__ void ce(unsigned int& a, unsigned int& b) {
    unsigned int lo = a < b ? a : b;
    unsigned int hi = a < b ? b : a;
    a = lo; b = hi;
}

// Sort 16 keys ascending — Batcher odd-even mergesort (63 CE, branchless).
__device__ __forceinline__ void sort16(unsigned int k[16]) {
#pragma unroll
    for (int p = 1; p < 16; p <<= 1)
#pragma unroll
        for (int q = p; q >= 1; q >>= 1)
#pragma unroll
            for (int j = q % p; j + q < 16; j += 2 * q)
#pragma unroll
                for (int i = 0; i < q; ++i) {
                    int x = i + j, y = i + j + q;
                    if (y < 16 && (x / (2 * p) == y / (2 * p))) ce(k[x], k[y]);
                }
}

// keys (sorted asc) <- lowest-16 of union(keys, nk), nk sorted asc.
__device__ __forceinline__ void merge16(unsigned int keys[16], const unsigned int nk[16]) {
    unsigned int t[16];
#pragma unroll
    for (int i = 0; i < 16; ++i) {
        unsigned int b = nk[15 - i];
        t[i] = keys[i] < b ? keys[i] : b;
    }
#pragma unroll
    for (int d = 8; d >= 1; d >>= 1)
#pragma unroll
        for (int i = 0; i < 16; ++i)
            if ((i & d) == 0) ce(t[i], t[i ^ d]);
#pragma unroll
    for (int i = 0; i < 16; ++i) keys[i] = t[i];
}

// ---------------------------------------------------------------------------
// prep3 (layer 0): sq + P/Q from x (D=3) + packed float4 (x,y,z,sq) sidecar.
// Wave = one row (64 h-lanes).
// ---------------------------------------------------------------------------
__global__ __launch_bounds__(256) void prep3_kernel(const float* __restrict__ x,
                                                    const float* __restrict__ w1,
                                                    const float* __restrict__ b1,
                                                    float* __restrict__ sqo,
                                                    float* __restrict__ P,
                                                    float* __restrict__ Q,
                                                    float* __restrict__ x4) {
    const int tid = threadIdx.x;
    const int h = tid & 63;
    const int pl = tid >> 6;
    const long p = (long)blockIdx.x * 4 + pl;
    const float* fp = x + p * 3;
    const float f0 = fp[0], f1 = fp[1], f2 = fp[2];
    if (h == 0) {
        const float s = f0 * f0 + f1 * f1 + f2 * f2;
        sqo[p] = s;
        *(float4*)(x4 + p * 4) = make_float4(f0, f1, f2, s);
    }
    float accp = 0.f, accq = 0.f;
    const float fv[3] = {f0, f1, f2};
#pragma unroll
    for (int d = 0; d < 3; ++d) {
        float wa = w1[d * HH + h];
        float wb = w1[(3 + d) * HH + h];
        accp = fmaf(fv[d], wa - wb, accp);
        accq = fmaf(fv[d], wb, accq);
    }
    P[p * HH + h] = accp + b1[h];
    Q[p * HH + h] = accq;
}

// ---------------------------------------------------------------------------
// prep64 (layers 1,2): fused bf16-convert + sq + P/Q. Block = 64 rows.
// ---------------------------------------------------------------------------
__global__ __launch_bounds__(256) void prep64_kernel(const float* __restrict__ feat,
                                                     const float* __restrict__ w1,
                                                     const float* __restrict__ b1,
                                                     __bf16* __restrict__ fbf,
                                                     float* __restrict__ sqo,
                                                     float* __restrict__ P,
                                                     float* __restrict__ Q) {
    __shared__ float rows[64 * HH];   // 16 KB
    const int tid = threadIdx.x;
    const int h = tid & 63;
    const int wv = tid >> 6;
    const long row0 = (long)blockIdx.x * 64;

    // loop-invariant weights -> VGPRs (coalesced, L1-resident after block 0)
    float wdiff[64], wbv[64];
#pragma unroll
    for (int d = 0; d < 64; ++d) {
        float wa = w1[d * HH + h];
        float wb_ = w1[(HH + d) * HH + h];
        wdiff[d] = wa - wb_;
        wbv[d] = wb_;
    }
    const float bv = b1[h];

    // stage 64 rows (coalesced float4)
    {
        const float4* src = (const float4*)(feat + row0 * HH);
        float4* dst = (float4*)rows;
#pragma unroll
        for (int i = 0; i < 4; ++i) dst[tid + 256 * i] = src[tid + 256 * i];
    }
    __syncthreads();

    // each wave handles 16 rows
    for (int r = wv * 16; r < wv * 16 + 16; ++r) {
        const long p = row0 + r;
        // transpose read (stride-1 per lane): bf16 convert + sq reduce
        float fvh = rows[r * HH + h];
        fbf[p * HH + h] = (__bf16)fvh;
        float s = fvh * fvh;
        s += __shfl_xor(s, 1);
        s += __shfl_xor(s, 2);
        s += __shfl_xor(s, 4);
        s += __shfl_xor(s, 8);
        s += __shfl_xor(s, 16);
        s += __shfl_xor(s, 32);
        if (h == 0) sqo[p] = s;

        float ap0 = 0.f, ap1 = 0.f, aq0 = 0.f, aq1 = 0.f;
#pragma unroll
        for (int d4 = 0; d4 < 16; ++d4) {
            float4 fv = *(const float4*)&rows[r * HH + d4 * 4];   // uniform -> broadcast
            ap0 = fmaf(fv.x, wdiff[4 * d4 + 0], ap0);
            aq0 = fmaf(fv.x, wbv[4 * d4 + 0], aq0);
            ap1 = fmaf(fv.y, wdiff[4 * d4 + 1], ap1);
            aq1 = fmaf(fv.y, wbv[4 * d4 + 1], aq1);
            ap0 = fmaf(fv.z, wdiff[4 * d4 + 2], ap0);
            aq0 = fmaf(fv.z, wbv[4 * d4 + 2], aq0);
            ap1 = fmaf(fv.w, wdiff[4 * d4 + 3], ap1);
            aq1 = fmaf(fv.w, wbv[4 * d4 + 3], aq1);
        }
        P[p * HH + h] = (ap0 + ap1) + bv;
        Q[p * HH + h] = aq0 + aq1;
    }
}

// ---------------------------------------------------------------------------
// Layer-0 kNN filter (D=3, fp32 scores, exact path preserved): WAVE-AUTONOMOUS.
// No LDS tile, no barriers: candidates stream directly from the packed x4
// buffer (quad-uniform broadcast loads, L1-hot). Interleaved slot partition.
// Epilogue cross-slot merge is intra-wave -> lgkmcnt fence only.
// ---------------------------------------------------------------------------
__global__ __launch_bounds__(256, 4) void knn3_filter_kernel(const float* __restrict__ x4,
                                                             unsigned short* __restrict__ idx32) {
    __shared__ unsigned int Km[64 * 68];   // epilogue staging only (17408 B)
    const int tid = threadIdx.x;
    // batch->XCD pinning: blocks with blockIdx%8==x land on XCD x (heuristic)
    const int xcd = blockIdx.x & 7;
    const int ii = blockIdx.x >> 3;          // 0..127
    const int b = xcd + 8 * (ii >> 5);       // 4 batches per XCD
    const int rg = ii & 31;
    const long pbase = (long)b * NN;
    const int r = tid >> 2, slot = tid & 3;
    const int row = rg * 64 + r;

    const f32x4 xr = *(const f32x4*)(x4 + (pbase + row) * 4);
    const float xr0 = xr[0], xr1 = xr[1], xr2 = xr[2];

    unsigned int keys[KK];
#pragma unroll
    for (int j = 0; j < KK; ++j) keys[j] = 0xFFFFFFFFu;

#pragma unroll 1
    for (int t = 0; t < NN / 256; ++t) {
        // selection over interleaved candidates: slot s -> cands 4*k + s
#pragma unroll
        for (int bb = 0; bb < 4; ++bb) {
            unsigned int nk[16];
#pragma unroll
            for (int cc = 0; cc < 16; ++cc) {
                const int li = bb * 64 + cc * 4 + slot;
                const f32x4 v = *(const f32x4*)(x4 + (pbase + t * 256 + li) * 4);
                float dot = fmaf(xr0, v[0], fmaf(xr1, v[1], xr2 * v[2]));
                float d2 = fmaf(-2.0f, dot, v[3]);   // sq_row dropped (rank-invariant)
                nk[cc] = packkey(d2, (unsigned int)(t * 256 + li));
            }
            sort16(nk);
            merge16(keys, nk);
        }
    }

    // merge: 4 sorted lists -> 2 x (lowest-16 of half-union) = 32 cands.
    // Writers and readers of row r are the SAME wave -> lgkmcnt fence only.
    {
        uint4* kw = (uint4*)&Km[r * 68 + slot * 16];
#pragma unroll
        for (int q = 0; q < 4; ++q)
            kw[q] = make_uint4(keys[4 * q], keys[4 * q + 1], keys[4 * q + 2], keys[4 * q + 3]);
    }
    asm volatile("s_waitcnt lgkmcnt(0)" ::: "memory");
    __builtin_amdgcn_sched_barrier(0);
    if (slot < 2) {
        const unsigned int* k0 = &Km[r * 68 + slot * 32];
        const unsigned int* k1 = k0 + 16;
        unsigned short ms[16];
#pragma unroll
        for (int j = 0; j < 16; ++j) {
            unsigned int a = k0[j], bv = k1[15 - j];
            ms[j] = (unsigned short)((a < bv ? a : bv) & 0x7FFu);
        }
        uint4* op = (uint4*)(idx32 + ((pbase + row) * 32 + slot * 16));
        op[0] = ((const uint4*)ms)[0];
        op[1] = ((const uint4*)ms)[1];
    }
}

// ---------------------------------------------------------------------------
// bf16-MFMA filter (D=64): WAVE-AUTONOMOUS. Block = 64 rows x 2048 cands.
// SWAPPED-OPERAND layout: D = mfma(cand_frag, row_frag) so lane (n16,quad) of
// wave wv holds 16 cands of ONE row (wv*16+n16) per tile. Cand fragments load
// DIRECTLY from global (coalesced 16B/lane, L1/L2-hot tile stream): no LDS
// staging, no barriers, no prefetch registers. Epilogue merge is intra-wave.
// ---------------------------------------------------------------------------
#define DPAD 68   // key staging stride (u32), epilogue only

__global__ __launch_bounds__(256, 4) void knn_filter_kernel(const __bf16* __restrict__ fbf,
                                                            const float* __restrict__ sq,
                                                            unsigned short* __restrict__ idx32) {
    __shared__ unsigned int Km[64 * DPAD];   // epilogue staging only (17408 B)

    const int tid = threadIdx.x;
    const int xcd = blockIdx.x & 7;
    const int ii = blockIdx.x >> 3;          // 0..127
    const int b = xcd + 8 * (ii >> 5);       // 4 batches per XCD
    const int rg = ii & 31;
    const long pbase = (long)b * NN;
    const int row0 = rg * 64;
    const int wv = tid >> 6, ln = tid & 63;
    const int n16 = ln & 15, quad = ln >> 4;

    // row fragments: load once, direct from global (L2-resident, 2x16B/lane)
    bf16x8 rf0, rf1;
    {
        const __bf16* rp = fbf + (pbase + row0 + wv * 16 + n16) * 64 + quad * 8;
        rf0 = *(const bf16x8*)rp;
        rf1 = *(const bf16x8*)(rp + 32);
    }

    unsigned int keys[KK];
#pragma unroll
    for (int j = 0; j < KK; ++j) keys[j] = 0xFFFFFFFFu;

#pragma unroll 1
    for (int t = 0; t < NN / 64; ++t) {
        unsigned int nk[16];
        // MFMA phase: D[cand][row] -> lane gets 16 cands of its own row
#pragma unroll
        for (int ct = 0; ct < 4; ++ct) {
            const __bf16* cp = fbf + (pbase + t * 64 + ct * 16 + n16) * 64 + quad * 8;
            bf16x8 cf0 = *(const bf16x8*)cp;          // coalesced: 16 rows x 64B
            bf16x8 cf1 = *(const bf16x8*)(cp + 32);
            f32x4 acc = {0.f, 0.f, 0.f, 0.f};
            acc = __builtin_amdgcn_mfma_f32_16x16x32_bf16(cf0, rf0, acc, 0, 0, 0);
            acc = __builtin_amdgcn_mfma_f32_16x16x32_bf16(cf1, rf1, acc, 0, 0, 0);
            const f32x4 sv = *(const f32x4*)(sq + pbase + t * 64 + ct * 16 + quad * 4);
            const unsigned int mb = (unsigned int)(t * 64 + ct * 16 + quad * 4);
#pragma unroll
            for (int rr = 0; rr < 4; ++rr)
                nk[ct * 4 + rr] = packkey(fmaf(-2.0f, acc[rr], sv[rr]), mb + rr);
        }
        // selection: pure-register sort + merge into persistent top-16
        sort16(nk);
        merge16(keys, nk);
    }

    // epilogue: stage all 4 slot-lists per row, then pairwise merge -> 32 cands.
    // Writers and readers of row r are the SAME wave -> lgkmcnt fence only.
    {
        uint4* kw = (uint4*)&Km[(wv * 16 + n16) * DPAD + quad * 16];
#pragma unroll
        for (int q = 0; q < 4; ++q)
            kw[q] = make_uint4(keys[4 * q], keys[4 * q + 1], keys[4 * q + 2], keys[4 * q + 3]);
    }
    asm volatile("s_waitcnt lgkmcnt(0)" ::: "memory");
    __builtin_amdgcn_sched_barrier(0);
    const int r = tid >> 2, slot = tid & 3;
    if (slot < 2) {
        const unsigned int* k0 = &Km[r * DPAD + slot * 32];
        const unsigned int* k1 = k0 + 16;
        unsigned short ms[16];
#pragma unroll
        for (int j = 0; j < 16; ++j) {
            unsigned int a = k0[j], bv = k1[15 - j];
            ms[j] = (unsigned short)((a < bv ? a : bv) & 0x7FFu);
        }
        uint4* op = (uint4*)(idx32 + ((pbase + row0 + r) * 32 + slot * 16));
        op[0] = ((const uint4*)ms)[0];
        op[1] = ((const uint4*)ms)[1];
    }
}

// ---------------------------------------------------------------------------
// Fused rescore + gather + edge-MLP — WAVE-AUTONOMOUS version.
// Each wave owns 2 rows end-to-end: no __syncthreads anywhere; cross-lane
// data moves via __shfl and wave-local LDS regions fenced with
// s_waitcnt lgkmcnt(0) + sched_barrier(0).
// Exact fp32 selection preserved via 43-bit packed (d2,j) u64 keys.
// ---------------------------------------------------------------------------
template <int D>
__global__ __launch_bounds__(256) void rescore_gather_kernel(const float* __restrict__ feat,
                                                             const float* __restrict__ sq,
                                                             const unsigned short* __restrict__ idx32,
                                                             const float* __restrict__ P,
                                                             const float* __restrict__ Q,
                                                             const float* __restrict__ wo,
                                                             const float* __restrict__ bo,
                                                             float* __restrict__ outf) {
    __shared__ unsigned long long ScK[4][2][32];   // per-wave packed (d2,j) keys
    __shared__ int Li[4][2][KK];                   // per-wave selected indices
    __shared__ float Rl[4][2][HH];                 // per-wave relu-mean

    const int tid = threadIdx.x;
    const int wv = tid >> 6, ln = tid & 63;
    const int rw = ln >> 5, c = ln & 31;
    // batch->XCD pinning: each XCD's L2 sees only 4 batches' gather set
    const int xcd = blockIdx.x & 7;
    const int ii = blockIdx.x >> 3;            // 0..1023
    const int batch = xcd + 8 * (ii >> 8);     // 4 batches per XCD
    const int rb = ii & 255;
    const long pbase = (long)batch * NN;
    const long pblk = pbase + (long)rb * 8;
    const int rA = wv * 2;                     // wave's first local row
    const long prow = pblk + rA + rw;          // lane's owned (row) for idx/rank

    // own candidate: lane (rw, c) owns cand c of row rA+rw
    const int jown = (int)idx32[prow * 32 + c];
    const float sqown = sq[pbase + jown];

    if constexpr (D == 64) {
        // quad-cooperative fp32 rescore: 4 lanes per cand, 64B granules
        const int cg = ln >> 2, e = ln & 3;
#pragma unroll
        for (int rr = 0; rr < 2; ++rr) {
            const float* rbase = feat + (pblk + rA + rr) * 64;
            const float4 rv0 = *(const float4*)(rbase + 0 * 16 + e * 4);
            const float4 rv1 = *(const float4*)(rbase + 1 * 16 + e * 4);
            const float4 rv2 = *(const float4*)(rbase + 2 * 16 + e * 4);
            const float4 rv3 = *(const float4*)(rbase + 3 * 16 + e * 4);
#pragma unroll
            for (int pp = 0; pp < 2; ++pp) {
                const int srcl = rr * 32 + pp * 16 + cg;
                const int jq = __shfl(jown, srcl);
                const float sqc = __shfl(sqown, srcl);
                const float* cb = feat + (pbase + jq) * 64;
                const float4 cv0 = *(const float4*)(cb + 0 * 16 + e * 4);
                const float4 cv1 = *(const float4*)(cb + 1 * 16 + e * 4);
                const float4 cv2 = *(const float4*)(cb + 2 * 16 + e * 4);
                const float4 cv3 = *(const float4*)(cb + 3 * 16 + e * 4);
                float part = 0.f;
                part = fmaf(rv0.x, cv0.x, part); part = fmaf(rv0.y, cv0.y, part);
                part = fmaf(rv0.z, cv0.z, part); part = fmaf(rv0.w, cv0.w, part);
                part = fmaf(rv1.x, cv1.x, part); part = fmaf(rv1.y, cv1.y, part);
                part = fmaf(rv1.z, cv1.z, part); part = fmaf(rv1.w, cv1.w, part);
                part = fmaf(rv2.x, cv2.x, part); part = fmaf(rv2.y, cv2.y, part);
                part = fmaf(rv2.z, cv2.z, part); part = fmaf(rv2.w, cv2.w, part);
                part = fmaf(rv3.x, cv3.x, part); part = fmaf(rv3.y, cv3.y, part);
                part = fmaf(rv3.z, cv3.z, part); part = fmaf(rv3.w, cv3.w, part);
                part += __shfl_xor(part, 1);
                part += __shfl_xor(part, 2);
                if (e == 0)
                    ScK[wv][rr][pp * 16 + cg] =
                        pack64(fmaf(-2.0f, part, sqc), (unsigned int)jq);
            }
        }
    } else {
        // D==3: lane computes its own cand's exact d2 directly
        const float* rp = feat + prow * 3;
        const float xr0 = rp[0], xr1 = rp[1], xr2 = rp[2];
        const float* cp = feat + (pbase + jown) * 3;
        const float dot = fmaf(xr0, cp[0], fmaf(xr1, cp[1], xr2 * cp[2]));
        ScK[wv][rw][c] = pack64(fmaf(-2.0f, dot, sqown), (unsigned int)jown);
    }
    asm volatile("s_waitcnt lgkmcnt(0)" ::: "memory");
    __builtin_amdgcn_sched_barrier(0);

    // rank: exact lexicographic (d2, j) via single u64 compare, LDS broadcast
    {
        const unsigned long long mykey = ScK[wv][rw][c];
        int rank = 0;
#pragma unroll
        for (int m = 0; m < 32; ++m)
            rank += (ScK[wv][rw][m] < mykey) ? 1 : 0;
        if (rank < KK) Li[wv][rw][rank] = (int)(mykey & 0x7FFu);
    }
    asm volatile("s_waitcnt lgkmcnt(0)" ::: "memory");
    __builtin_amdgcn_sched_barrier(0);

    // Phase 2: Q-gather + relu-mean + wo matmul; lane = h, 2 rows per wave
    const int h = ln;
    const long pA = pblk + rA;
    const float PvA = P[pA * HH + h];
    const float PvB = P[(pA + 1) * HH + h];
    float accA = 0.f, accB = 0.f;
#pragma unroll
    for (int kq = 0; kq < 4; ++kq) {
        const int4 a4 = *(const int4*)&Li[wv][0][kq * 4];   // uniform -> broadcast
        const int4 b4 = *(const int4*)&Li[wv][1][kq * 4];
        accA += fmaxf(PvA + Q[(pbase + a4.x) * HH + h], 0.f);
        accA += fmaxf(PvA + Q[(pbase + a4.y) * HH + h], 0.f);
        accA += fmaxf(PvA + Q[(pbase + a4.z) * HH + h], 0.f);
        accA += fmaxf(PvA + Q[(pbase + a4.w) * HH + h], 0.f);
        accB += fmaxf(PvB + Q[(pbase + b4.x) * HH + h], 0.f);
        accB += fmaxf(PvB + Q[(pbase + b4.y) * HH + h], 0.f);
        accB += fmaxf(PvB + Q[(pbase + b4.z) * HH + h], 0.f);
        accB += fmaxf(PvB + Q[(pbase + b4.w) * HH + h], 0.f);
    }
    Rl[wv][0][h] = accA * (1.f / KK);
    Rl[wv][1][h] = accB * (1.f / KK);
    asm volatile("s_waitcnt lgkmcnt(0)" ::: "memory");
    __builtin_amdgcn_sched_barrier(0);

    float oA = bo[h];
    float oB = oA;
#pragma unroll
    for (int l4 = 0; l4 < 16; ++l4) {
        const float4 ra = *(const float4*)&Rl[wv][0][l4 * 4];   // uniform broadcast
        const float4 rb4 = *(const float4*)&Rl[wv][1][l4 * 4];
        const float* wp = wo + (l4 * 4) * HH + h;               // L1-hot, shared A/B
        const float w0 = wp[0], w1 = wp[HH], w2 = wp[2 * HH], w3 = wp[3 * HH];
        oA = fmaf(ra.x, w0, oA);  oB = fmaf(rb4.x, w0, oB);
        oA = fmaf(ra.y, w1, oA);  oB = fmaf(rb4.y, w1, oB);
        oA = fmaf(ra.z, w2, oA);  oB = fmaf(rb4.z, w2, oB);
        oA = fmaf(ra.w, w3, oA);  oB = fmaf(rb4.w, w3, oB);
    }
    outf[pA * HH + h] = oA;
    outf[(pA + 1) * HH + h] = oB;
}

// ---------------------------------------------------------------------------
// pool partial: block = (batch, chunk of 8); sums 256 rows -> pp[batch][ch][64]
// ---------------------------------------------------------------------------
__global__ __launch_bounds__(256) void pool_partial_kernel(const float* __restrict__ feat,
                                                           float* __restrict__ pp) {
    __shared__ float part[4][HH];
    const int batch = blockIdx.x >> 3;
    const int chk = blockIdx.x & 7;
    const int tid = threadIdx.x;
    const int h = tid & 63;
    const int sub = tid >> 6;
    float s = 0.f;
    const float* fp = feat + ((long)batch * NN + chk * 256 + sub * 64) * HH + h;
    for (int n = 0; n < 64; ++n) s += fp[(long)n * HH];
    part[sub][h] = s;
    __syncthreads();
    if (tid < HH)
        pp[(batch * 8 + chk) * HH + h] = part[0][h] + part[1][h] + part[2][h] + part[3][h];
}

// ---------------------------------------------------------------------------
// head: g[b] = mean; out[b] = relu(g@fw1+fb1)@fw2+fb2. Block = batch.
// ---------------------------------------------------------------------------
__global__ __launch_bounds__(256) void head_kernel(const float* __restrict__ pp,
                                                   const float* __restrict__ fw1,
                                                   const float* __restrict__ fb1,
                                                   const float* __restrict__ fw2,
                                                   const float* __restrict__ fb2,
                                                   float* __restrict__ out) {
    __shared__ float g[HH];
    __shared__ float tl[HH];
    const int b = blockIdx.x;
    const int tid = threadIdx.x;
    if (tid < HH) {
        float s = 0.f;
#pragma unroll
        for (int c = 0; c < 8; ++c) s += pp[(b * 8 + c) * HH + tid];
        g[tid] = s * (1.f / NN);
    }
    __syncthreads();
    if (tid < HH) {
        float a = fb1[tid];
#pragma unroll
        for (int l = 0; l < HH; ++l) a = fmaf(g[l], fw1[l * HH + tid], a);
        tl[tid] = fmaxf(a, 0.f);
    }
    __syncthreads();
    if (tid < OUTC) {
        float o = fb2[tid];
#pragma unroll
        for (int l = 0; l < HH; ++l) o = fmaf(tl[l], fw2[l * OUTC + tid], o);
        out[(long)b * OUTC + tid] = o;
    }
}

// ---------------------------------------------------------------------------
extern "C" void kernel_launch(void* const* d_in, const int* in_sizes, int n_in,
                              void* d_out, int out_size, void* d_ws, size_t ws_size,
                              hipStream_t stream) {
    const float* x    = (const float*)d_in[0];
    const float* w1_0 = (const float*)d_in[1];
    const float* b1_0 = (const float*)d_in[2];
    const float* wo_0 = (const float*)d_in[3];
    const float* bo_0 = (const float*)d_in[4];
    const float* w1_1 = (const float*)d_in[5];
    const float* b1_1 = (const float*)d_in[6];
    const float* wo_1 = (const float*)d_in[7];
    const float* bo_1 = (const float*)d_in[8];
    const float* w1_2 = (const float*)d_in[9];
    const float* b1_2 = (const float*)d_in[10];
    const float* wo_2 = (const float*)d_in[11];
    const float* bo_2 = (const float*)d_in[12];
    const float* fw1  = (const float*)d_in[13];
    const float* fb1  = (const float*)d_in[14];
    const float* fw2  = (const float*)d_in[15];
    const float* fb2  = (const float*)d_in[16];
    float* out = (float*)d_out;

    // workspace layout (floats)
    float* featA = (float*)d_ws;
    float* featB = featA + (long)BN * HH;
    float* Pb    = featB + (long)BN * HH;
    float* Qb    = Pb + (long)BN * HH;
    float* sqb   = Qb + (long)BN * HH;
    unsigned short* idx32 = (unsigned short*)(sqb + BN);     // BN x 32 u16
    float* ppb   = (float*)(idx32 + (long)BN * 32);          // 32 x 8 x 64
    float* x4b   = ppb + 32 * 8 * HH;                        // BN x 4 packed (x,y,z,sq)

    // bf16 feature mirrors alias the OPPOSITE feature buffer (consumed by the
    // filter before rescore_gather rewrites that buffer)
    __bf16* fbf1 = (__bf16*)featB;   // layer 1 (featB rewritten after filter)
    __bf16* fbf2 = (__bf16*)featA;   // layer 2 (featA rewritten after filter)

    // ---- layer 0 (D=3, exact fp32 kNN) ----
    prep3_kernel<<<BN / 4, 256, 0, stream>>>(x, w1_0, b1_0, sqb, Pb, Qb, x4b);
    knn3_filter_kernel<<<BB * 32, 256, 0, stream>>>(x4b, idx32);
    rescore_gather_kernel<3><<<BN / 8, 256, 0, stream>>>(x, sqb, idx32, Pb, Qb, wo_0, bo_0, featA);

    // ---- layer 1 (D=64) ----
    prep64_kernel<<<BN / 64, 256, 0, stream>>>(featA, w1_1, b1_1, fbf1, sqb, Pb, Qb);
    knn_filter_kernel<<<BB * 32, 256, 0, stream>>>(fbf1, sqb, idx32);
    rescore_gather_kernel<64><<<BN / 8, 256, 0, stream>>>(featA, sqb, idx32, Pb, Qb, wo_1, bo_1, featB);

    // ---- layer 2 (D=64) ----
    prep64_kernel<<<BN / 64, 256, 0, stream>>>(featB, w1_2, b1_2, fbf2, sqb, Pb, Qb);
    knn_filter_kernel<<<BB * 32, 256, 0, stream>>>(fbf2, sqb, idx32);
    rescore_gather_kernel<64><<<BN / 8, 256, 0, stream>>>(featB, sqb, idx32, Pb, Qb, wo_2, bo_2, featA);

    // ---- pool + head ----
    pool_partial_kernel<<<BB * 8, 256, 0, stream>>>(featA, ppb);
    head_kernel<<<BB, 256, 0, stream>>>(ppb, fw1, fb1, fw2, fb2, out);
}

// Round 6
// 667.031 us; speedup vs baseline: 1.0183x; 1.0183x over previous
//
#include <hip/hip_runtime.h>

// Problem constants
#define BB 32
#define NN 2048
#define FF 3
#define HH 64
#define OUTC 128
#define KK 16
#define BN (BB * NN)   // 65536 points

typedef __attribute__((ext_vector_type(8))) __bf16 bf16x8;
typedef __attribute__((ext_vector_type(4))) float f32x4;

// Pack d2 + candidate index into one sortable u32:
// high 21 bits = monotone(float d2) truncated, low 11 bits = idx (NN=2^11).
__device__ __forceinline__ unsigned int packkey(float d2, unsigned int m) {
    unsigned int bb = __builtin_bit_cast(unsigned int, d2);
    unsigned int msk = (unsigned int)((int)bb >> 31);
    unsigned int srt = bb ^ (msk | 0x80000000u);
    return (srt & 0xFFFFF800u) | m;
}

// Full-precision sortable key: 32-bit monotone(f32) << 11 | idx. Lexicographic
// (d2, j) order in a single u64 compare — exact, tie-break on smaller index.
__device__ __forceinline__ unsigned long long pack64(float d2, unsigned int j) {
    unsigned int bb = __builtin_bit_cast(unsigned int, d2);
    unsigned int msk = (unsigned int)((int)bb >> 31);
    unsigned int srt = bb ^ (msk | 0x80000000u);
    return ((unsigned long long)srt << 11) | j;
}

__device__ __forceinline__ void ce(unsigned int& a, unsigned int& b) {
    unsigned int lo = a < b ? a : b;
    unsigned int hi = a < b ? b : a;
    a = lo; b = hi;
}

// Sort 16 keys ascending — Batcher odd-even mergesort (63 CE, branchless).
__device__ __forceinline__ void sort16(unsigned int k[16]) {
#pragma unroll
    for (int p = 1; p < 16; p <<= 1)
#pragma unroll
        for (int q = p; q >= 1; q >>= 1)
#pragma unroll
            for (int j = q % p; j + q < 16; j += 2 * q)
#pragma unroll
                for (int i = 0; i < q; ++i) {
                    int x = i + j, y = i + j + q;
                    if (y < 16 && (x / (2 * p) == y / (2 * p))) ce(k[x], k[y]);
                }
}

// keys (sorted asc) <- lowest-16 of union(keys, nk), nk sorted asc.
__device__ __forceinline__ void merge16(unsigned int keys[16], const unsigned int nk[16]) {
    unsigned int t[16];
#pragma unroll
    for (int i = 0; i < 16; ++i) {
        unsigned int b = nk[15 - i];
        t[i] = keys[i] < b ? keys[i] : b;
    }
#pragma unroll
    for (int d = 8; d >= 1; d >>= 1)
#pragma unroll
        for (int i = 0; i < 16; ++i)
            if ((i & d) == 0) ce(t[i], t[i ^ d]);
#pragma unroll
    for (int i = 0; i < 16; ++i) keys[i] = t[i];
}

// ---------------------------------------------------------------------------
// prep3 (layer 0): sq + P/Q from x (D=3). Wave = one row (64 h-lanes).
// ---------------------------------------------------------------------------
__global__ __launch_bounds__(256) void prep3_kernel(const float* __restrict__ x,
                                                    const float* __restrict__ w1,
                                                    const float* __restrict__ b1,
                                                    float* __restrict__ sqo,
                                                    float* __restrict__ P,
                                                    float* __restrict__ Q) {
    const int tid = threadIdx.x;
    const int h = tid & 63;
    const int pl = tid >> 6;
    const long p = (long)blockIdx.x * 4 + pl;
    const float* fp = x + p * 3;
    const float f0 = fp[0], f1 = fp[1], f2 = fp[2];
    if (h == 0) sqo[p] = f0 * f0 + f1 * f1 + f2 * f2;
    float accp = 0.f, accq = 0.f;
    const float fv[3] = {f0, f1, f2};
#pragma unroll
    for (int d = 0; d < 3; ++d) {
        float wa = w1[d * HH + h];
        float wb = w1[(3 + d) * HH + h];
        accp = fmaf(fv[d], wa - wb, accp);
        accq = fmaf(fv[d], wb, accq);
    }
    P[p * HH + h] = accp + b1[h];
    Q[p * HH + h] = accq;
}

// ---------------------------------------------------------------------------
// prep64 (layers 1,2): fused bf16-convert + sq + P/Q. Block = 64 rows.
// ---------------------------------------------------------------------------
__global__ __launch_bounds__(256) void prep64_kernel(const float* __restrict__ feat,
                                                     const float* __restrict__ w1,
                                                     const float* __restrict__ b1,
                                                     __bf16* __restrict__ fbf,
                                                     float* __restrict__ sqo,
                                                     float* __restrict__ P,
                                                     float* __restrict__ Q) {
    __shared__ float rows[64 * HH];   // 16 KB
    const int tid = threadIdx.x;
    const int h = tid & 63;
    const int wv = tid >> 6;
    const long row0 = (long)blockIdx.x * 64;

    // loop-invariant weights -> VGPRs (coalesced, L1-resident after block 0)
    float wdiff[64], wbv[64];
#pragma unroll
    for (int d = 0; d < 64; ++d) {
        float wa = w1[d * HH + h];
        float wb_ = w1[(HH + d) * HH + h];
        wdiff[d] = wa - wb_;
        wbv[d] = wb_;
    }
    const float bv = b1[h];

    // stage 64 rows (coalesced float4)
    {
        const float4* src = (const float4*)(feat + row0 * HH);
        float4* dst = (float4*)rows;
#pragma unroll
        for (int i = 0; i < 4; ++i) dst[tid + 256 * i] = src[tid + 256 * i];
    }
    __syncthreads();

    // each wave handles 16 rows
    for (int r = wv * 16; r < wv * 16 + 16; ++r) {
        const long p = row0 + r;
        // transpose read (stride-1 per lane): bf16 convert + sq reduce
        float fvh = rows[r * HH + h];
        fbf[p * HH + h] = (__bf16)fvh;
        float s = fvh * fvh;
        s += __shfl_xor(s, 1);
        s += __shfl_xor(s, 2);
        s += __shfl_xor(s, 4);
        s += __shfl_xor(s, 8);
        s += __shfl_xor(s, 16);
        s += __shfl_xor(s, 32);
        if (h == 0) sqo[p] = s;

        float ap0 = 0.f, ap1 = 0.f, aq0 = 0.f, aq1 = 0.f;
#pragma unroll
        for (int d4 = 0; d4 < 16; ++d4) {
            float4 fv = *(const float4*)&rows[r * HH + d4 * 4];   // uniform -> broadcast
            ap0 = fmaf(fv.x, wdiff[4 * d4 + 0], ap0);
            aq0 = fmaf(fv.x, wbv[4 * d4 + 0], aq0);
            ap1 = fmaf(fv.y, wdiff[4 * d4 + 1], ap1);
            aq1 = fmaf(fv.y, wbv[4 * d4 + 1], aq1);
            ap0 = fmaf(fv.z, wdiff[4 * d4 + 2], ap0);
            aq0 = fmaf(fv.z, wbv[4 * d4 + 2], aq0);
            ap1 = fmaf(fv.w, wdiff[4 * d4 + 3], ap1);
            aq1 = fmaf(fv.w, wbv[4 * d4 + 3], aq1);
        }
        P[p * HH + h] = (ap0 + ap1) + bv;
        Q[p * HH + h] = aq0 + aq1;
    }
}

// ---------------------------------------------------------------------------
// Layer-0 kNN filter (D=3, fp32 scores, exact path preserved): block = 64
// rows x 2048 cands. Round-2 two-barrier structure (36 VGPR, selection after
// staging) + INTERLEAVED slot partition (slot s owns cands c%4==s): the 4
// slots read 4 consecutive float4s -> 16 banks, broadcast across rows, zero
// conflicts. (r3 lesson: single-barrier dbuf -> 148 VGPR, occupancy 11%.)
// ---------------------------------------------------------------------------
__global__ __launch_bounds__(256) void knn3_filter_kernel(const float* __restrict__ x,
                                                          const float* __restrict__ sq,
                                                          unsigned short* __restrict__ idx32) {
    __shared__ float4 lds_c[256];
    __shared__ unsigned int Km[64 * 68];
    const int tid = threadIdx.x;
    // batch->XCD pinning: blocks with blockIdx%8==x land on XCD x (heuristic)
    const int xcd = blockIdx.x & 7;
    const int ii = blockIdx.x >> 3;          // 0..127
    const int b = xcd + 8 * (ii >> 5);       // 4 batches per XCD
    const int rg = ii & 31;
    const long pbase = (long)b * NN;
    const int r = tid >> 2, slot = tid & 3;
    const int row = rg * 64 + r;

    const float* rp = x + (pbase + row) * 3;
    const float xr0 = rp[0], xr1 = rp[1], xr2 = rp[2];

    unsigned int keys[KK];
#pragma unroll
    for (int j = 0; j < KK; ++j) keys[j] = 0xFFFFFFFFu;

    // preload tile 0
    float c0, c1, c2, c3;
    {
        const float* cp = x + (pbase + tid) * 3;
        c0 = cp[0]; c1 = cp[1]; c2 = cp[2]; c3 = sq[pbase + tid];
    }

    for (int t = 0; t < NN / 256; ++t) {
        __syncthreads();                      // prev selection done reading lds_c
        lds_c[tid] = make_float4(c0, c1, c2, c3);
        __syncthreads();                      // tile ready
        if (t < NN / 256 - 1) {               // prefetch next tile (hidden by selection)
            const int m = (t + 1) * 256 + tid;
            const float* cp = x + (pbase + m) * 3;
            c0 = cp[0]; c1 = cp[1]; c2 = cp[2]; c3 = sq[pbase + m];
        }
        // selection over interleaved candidates: slot s -> cands 4*k + s
#pragma unroll
        for (int bb = 0; bb < 4; ++bb) {
            unsigned int nk[16];
#pragma unroll
            for (int cc = 0; cc < 16; ++cc) {
                const int li = bb * 64 + cc * 4 + slot;
                float4 v = lds_c[li];
                float dot = fmaf(xr0, v.x, fmaf(xr1, v.y, xr2 * v.z));
                float d2 = fmaf(-2.0f, dot, v.w);   // sq_row dropped (rank-invariant)
                nk[cc] = packkey(d2, (unsigned int)(t * 256 + li));
            }
            sort16(nk);
            merge16(keys, nk);
        }
    }

    // merge: 4 sorted lists -> 2 x (lowest-16 of half-union) = 32 cands
    {
        uint4* kw = (uint4*)&Km[r * 68 + slot * 16];
#pragma unroll
        for (int q = 0; q < 4; ++q)
            kw[q] = make_uint4(keys[4 * q], keys[4 * q + 1], keys[4 * q + 2], keys[4 * q + 3]);
    }
    __syncthreads();
    if (slot < 2) {
        const unsigned int* k0 = &Km[r * 68 + slot * 32];
        const unsigned int* k1 = k0 + 16;
        unsigned short ms[16];
#pragma unroll
        for (int j = 0; j < 16; ++j) {
            unsigned int a = k0[j], bv = k1[15 - j];
            ms[j] = (unsigned short)((a < bv ? a : bv) & 0x7FFu);
        }
        uint4* op = (uint4*)(idx32 + ((pbase + row) * 32 + slot * 16));
        op[0] = ((const uint4*)ms)[0];
        op[1] = ((const uint4*)ms)[1];
    }
}

// ---------------------------------------------------------------------------
// bf16-MFMA filter (D=64): WAVE-AUTONOMOUS with REGISTER DOUBLE-BUFFERING.
// Swapped-operand MFMA: lane (n16,quad) of wave wv gets 16 cands of row
// (wv*16+n16) per 64-cand tile, all from lane-private global loads (coalesced
// 16B/lane, L1-hot: all 4 waves read the same cand tiles). Two named register
// sets ca/cbuf (compile-time indices only): tile t+1's 8 loads are issued
// before tile t's ~600-cycle sort/merge, hiding L2 latency (r5 lesson: without
// prefetch, load-use stalls dropped VALUBusy to 43%). No LDS, no barriers in
// the main loop; epilogue merge is intra-wave (lgkmcnt fence only).
// ---------------------------------------------------------------------------
#define DPAD 68   // key staging stride (u32), epilogue only

__device__ __forceinline__ void load_tile(bf16x8 (&dst)[8], const __bf16* __restrict__ p) {
#pragma unroll
    for (int ct = 0; ct < 4; ++ct) {
        dst[2 * ct]     = *(const bf16x8*)(p + ct * 16 * 64);
        dst[2 * ct + 1] = *(const bf16x8*)(p + ct * 16 * 64 + 32);
    }
}

__device__ __forceinline__ void compute_tile(const bf16x8 (&cf)[8], bf16x8 rf0, bf16x8 rf1,
                                             const float* __restrict__ sqp, int tbase, int quad,
                                             unsigned int keys[16]) {
    unsigned int nk[16];
#pragma unroll
    for (int ct = 0; ct < 4; ++ct) {
        f32x4 acc = {0.f, 0.f, 0.f, 0.f};
        acc = __builtin_amdgcn_mfma_f32_16x16x32_bf16(cf[2 * ct], rf0, acc, 0, 0, 0);
        acc = __builtin_amdgcn_mfma_f32_16x16x32_bf16(cf[2 * ct + 1], rf1, acc, 0, 0, 0);
        const f32x4 sv = *(const f32x4*)(sqp + ct * 16 + quad * 4);
        const unsigned int mb = (unsigned int)(tbase + ct * 16 + quad * 4);
#pragma unroll
        for (int rr = 0; rr < 4; ++rr)
            nk[ct * 4 + rr] = packkey(fmaf(-2.0f, acc[rr], sv[rr]), mb + rr);
    }
    sort16(nk);
    merge16(keys, nk);
}

__global__ __launch_bounds__(256, 4) void knn_filter_kernel(const __bf16* __restrict__ fbf,
                                                            const float* __restrict__ sq,
                                                            unsigned short* __restrict__ idx32) {
    __shared__ unsigned int Km[64 * DPAD];   // epilogue staging only (17408 B)

    const int tid = threadIdx.x;
    const int xcd = blockIdx.x & 7;
    const int ii = blockIdx.x >> 3;          // 0..127
    const int b = xcd + 8 * (ii >> 5);       // 4 batches per XCD
    const int rg = ii & 31;
    const long pbase = (long)b * NN;
    const int row0 = rg * 64;
    const int wv = tid >> 6, ln = tid & 63;
    const int n16 = ln & 15, quad = ln >> 4;

    // row fragments: load once, direct from global (L2-resident, 2x16B/lane)
    bf16x8 rf0, rf1;
    {
        const __bf16* rp = fbf + (pbase + row0 + wv * 16 + n16) * 64 + quad * 8;
        rf0 = *(const bf16x8*)rp;
        rf1 = *(const bf16x8*)(rp + 32);
    }

    unsigned int keys[KK];
#pragma unroll
    for (int j = 0; j < KK; ++j) keys[j] = 0xFFFFFFFFu;

    // lane-private cand fragment base: row n16 (+tile offset), dims quad*8
    const __bf16* cb0 = fbf + (pbase + n16) * 64 + quad * 8;
    const float* sqb_ = sq + pbase;

    bf16x8 ca[8], cbuf[8];
    load_tile(ca, cb0);                       // tile 0
#pragma unroll 1
    for (int i = 0; i < 16; ++i) {
        load_tile(cbuf, cb0 + (long)(2 * i + 1) * 4096);       // prefetch odd tile
        compute_tile(ca, rf0, rf1, sqb_ + (2 * i) * 64, (2 * i) * 64, quad, keys);
        if (i < 15)
            load_tile(ca, cb0 + (long)(2 * i + 2) * 4096);     // prefetch even tile
        compute_tile(cbuf, rf0, rf1, sqb_ + (2 * i + 1) * 64, (2 * i + 1) * 64, quad, keys);
    }

    // epilogue: stage all 4 slot-lists per row, then pairwise merge -> 32 cands.
    // Writers and readers of row r are the SAME wave -> lgkmcnt fence only.
    {
        uint4* kw = (uint4*)&Km[(wv * 16 + n16) * DPAD + quad * 16];
#pragma unroll
        for (int q = 0; q < 4; ++q)
            kw[q] = make_uint4(keys[4 * q], keys[4 * q + 1], keys[4 * q + 2], keys[4 * q + 3]);
    }
    asm volatile("s_waitcnt lgkmcnt(0)" ::: "memory");
    __builtin_amdgcn_sched_barrier(0);
    const int r = tid >> 2, slot = tid & 3;
    if (slot < 2) {
        const unsigned int* k0 = &Km[r * DPAD + slot * 32];
        const unsigned int* k1 = k0 + 16;
        unsigned short ms[16];
#pragma unroll
        for (int j = 0; j < 16; ++j) {
            unsigned int a = k0[j], bv = k1[15 - j];
            ms[j] = (unsigned short)((a < bv ? a : bv) & 0x7FFu);
        }
        uint4* op = (uint4*)(idx32 + ((pbase + row0 + r) * 32 + slot * 16));
        op[0] = ((const uint4*)ms)[0];
        op[1] = ((const uint4*)ms)[1];
    }
}

// ---------------------------------------------------------------------------
// Fused rescore + gather + edge-MLP — WAVE-AUTONOMOUS version.
// Each wave owns 2 rows end-to-end: no __syncthreads anywhere; cross-lane
// data moves via __shfl and wave-local LDS regions fenced with
// s_waitcnt lgkmcnt(0) + sched_barrier(0).
// Exact fp32 selection preserved via 43-bit packed (d2,j) u64 keys.
// ---------------------------------------------------------------------------
template <int D>
__global__ __launch_bounds__(256) void rescore_gather_kernel(const float* __restrict__ feat,
                                                             const float* __restrict__ sq,
                                                             const unsigned short* __restrict__ idx32,
                                                             const float* __restrict__ P,
                                                             const float* __restrict__ Q,
                                                             const float* __restrict__ wo,
                                                             const float* __restrict__ bo,
                                                             float* __restrict__ outf) {
    __shared__ unsigned long long ScK[4][2][32];   // per-wave packed (d2,j) keys
    __shared__ int Li[4][2][KK];                   // per-wave selected indices
    __shared__ float Rl[4][2][HH];                 // per-wave relu-mean

    const int tid = threadIdx.x;
    const int wv = tid >> 6, ln = tid & 63;
    const int rw = ln >> 5, c = ln & 31;
    // batch->XCD pinning: each XCD's L2 sees only 4 batches' gather set
    const int xcd = blockIdx.x & 7;
    const int ii = blockIdx.x >> 3;            // 0..1023
    const int batch = xcd + 8 * (ii >> 8);     // 4 batches per XCD
    const int rb = ii & 255;
    const long pbase = (long)batch * NN;
    const long pblk = pbase + (long)rb * 8;
    const int rA = wv * 2;                     // wave's first local row
    const long prow = pblk + rA + rw;          // lane's owned (row) for idx/rank

    // own candidate: lane (rw, c) owns cand c of row rA+rw
    const int jown = (int)idx32[prow * 32 + c];
    const float sqown = sq[pbase + jown];

    if constexpr (D == 64) {
        // quad-cooperative fp32 rescore: 4 lanes per cand, 64B granules
        const int cg = ln >> 2, e = ln & 3;
#pragma unroll
        for (int rr = 0; rr < 2; ++rr) {
            const float* rbase = feat + (pblk + rA + rr) * 64;
            const float4 rv0 = *(const float4*)(rbase + 0 * 16 + e * 4);
            const float4 rv1 = *(const float4*)(rbase + 1 * 16 + e * 4);
            const float4 rv2 = *(const float4*)(rbase + 2 * 16 + e * 4);
            const float4 rv3 = *(const float4*)(rbase + 3 * 16 + e * 4);
#pragma unroll
            for (int pp = 0; pp < 2; ++pp) {
                const int srcl = rr * 32 + pp * 16 + cg;
                const int jq = __shfl(jown, srcl);
                const float sqc = __shfl(sqown, srcl);
                const float* cb = feat + (pbase + jq) * 64;
                const float4 cv0 = *(const float4*)(cb + 0 * 16 + e * 4);
                const float4 cv1 = *(const float4*)(cb + 1 * 16 + e * 4);
                const float4 cv2 = *(const float4*)(cb + 2 * 16 + e * 4);
                const float4 cv3 = *(const float4*)(cb + 3 * 16 + e * 4);
                float part = 0.f;
                part = fmaf(rv0.x, cv0.x, part); part = fmaf(rv0.y, cv0.y, part);
                part = fmaf(rv0.z, cv0.z, part); part = fmaf(rv0.w, cv0.w, part);
                part = fmaf(rv1.x, cv1.x, part); part = fmaf(rv1.y, cv1.y, part);
                part = fmaf(rv1.z, cv1.z, part); part = fmaf(rv1.w, cv1.w, part);
                part = fmaf(rv2.x, cv2.x, part); part = fmaf(rv2.y, cv2.y, part);
                part = fmaf(rv2.z, cv2.z, part); part = fmaf(rv2.w, cv2.w, part);
                part = fmaf(rv3.x, cv3.x, part); part = fmaf(rv3.y, cv3.y, part);
                part = fmaf(rv3.z, cv3.z, part); part = fmaf(rv3.w, cv3.w, part);
                part += __shfl_xor(part, 1);
                part += __shfl_xor(part, 2);
                if (e == 0)
                    ScK[wv][rr][pp * 16 + cg] =
                        pack64(fmaf(-2.0f, part, sqc), (unsigned int)jq);
            }
        }
    } else {
        // D==3: lane computes its own cand's exact d2 directly
        const float* rp = feat + prow * 3;
        const float xr0 = rp[0], xr1 = rp[1], xr2 = rp[2];
        const float* cp = feat + (pbase + jown) * 3;
        const float dot = fmaf(xr0, cp[0], fmaf(xr1, cp[1], xr2 * cp[2]));
        ScK[wv][rw][c] = pack64(fmaf(-2.0f, dot, sqown), (unsigned int)jown);
    }
    asm volatile("s_waitcnt lgkmcnt(0)" ::: "memory");
    __builtin_amdgcn_sched_barrier(0);

    // rank: exact lexicographic (d2, j) via single u64 compare, LDS broadcast
    {
        const unsigned long long mykey = ScK[wv][rw][c];
        int rank = 0;
#pragma unroll
        for (int m = 0; m < 32; ++m)
            rank += (ScK[wv][rw][m] < mykey) ? 1 : 0;
        if (rank < KK) Li[wv][rw][rank] = (int)(mykey & 0x7FFu);
    }
    asm volatile("s_waitcnt lgkmcnt(0)" ::: "memory");
    __builtin_amdgcn_sched_barrier(0);

    // Phase 2: Q-gather + relu-mean + wo matmul; lane = h, 2 rows per wave
    const int h = ln;
    const long pA = pblk + rA;
    const float PvA = P[pA * HH + h];
    const float PvB = P[(pA + 1) * HH + h];
    float accA = 0.f, accB = 0.f;
#pragma unroll
    for (int kq = 0; kq < 4; ++kq) {
        const int4 a4 = *(const int4*)&Li[wv][0][kq * 4];   // uniform -> broadcast
        const int4 b4 = *(const int4*)&Li[wv][1][kq * 4];
        accA += fmaxf(PvA + Q[(pbase + a4.x) * HH + h], 0.f);
        accA += fmaxf(PvA + Q[(pbase + a4.y) * HH + h], 0.f);
        accA += fmaxf(PvA + Q[(pbase + a4.z) * HH + h], 0.f);
        accA += fmaxf(PvA + Q[(pbase + a4.w) * HH + h], 0.f);
        accB += fmaxf(PvB + Q[(pbase + b4.x) * HH + h], 0.f);
        accB += fmaxf(PvB + Q[(pbase + b4.y) * HH + h], 0.f);
        accB += fmaxf(PvB + Q[(pbase + b4.z) * HH + h], 0.f);
        accB += fmaxf(PvB + Q[(pbase + b4.w) * HH + h], 0.f);
    }
    Rl[wv][0][h] = accA * (1.f / KK);
    Rl[wv][1][h] = accB * (1.f / KK);
    asm volatile("s_waitcnt lgkmcnt(0)" ::: "memory");
    __builtin_amdgcn_sched_barrier(0);

    float oA = bo[h];
    float oB = oA;
#pragma unroll
    for (int l4 = 0; l4 < 16; ++l4) {
        const float4 ra = *(const float4*)&Rl[wv][0][l4 * 4];   // uniform broadcast
        const float4 rb4 = *(const float4*)&Rl[wv][1][l4 * 4];
        const float* wp = wo + (l4 * 4) * HH + h;               // L1-hot, shared A/B
        const float w0 = wp[0], w1 = wp[HH], w2 = wp[2 * HH], w3 = wp[3 * HH];
        oA = fmaf(ra.x, w0, oA);  oB = fmaf(rb4.x, w0, oB);
        oA = fmaf(ra.y, w1, oA);  oB = fmaf(rb4.y, w1, oB);
        oA = fmaf(ra.z, w2, oA);  oB = fmaf(rb4.z, w2, oB);
        oA = fmaf(ra.w, w3, oA);  oB = fmaf(rb4.w, w3, oB);
    }
    outf[pA * HH + h] = oA;
    outf[(pA + 1) * HH + h] = oB;
}

// ---------------------------------------------------------------------------
// pool partial: block = (batch, chunk of 8); sums 256 rows -> pp[batch][ch][64]
// ---------------------------------------------------------------------------
__global__ __launch_bounds__(256) void pool_partial_kernel(const float* __restrict__ feat,
                                                           float* __restrict__ pp) {
    __shared__ float part[4][HH];
    const int batch = blockIdx.x >> 3;
    const int chk = blockIdx.x & 7;
    const int tid = threadIdx.x;
    const int h = tid & 63;
    const int sub = tid >> 6;
    float s = 0.f;
    const float* fp = feat + ((long)batch * NN + chk * 256 + sub * 64) * HH + h;
    for (int n = 0; n < 64; ++n) s += fp[(long)n * HH];
    part[sub][h] = s;
    __syncthreads();
    if (tid < HH)
        pp[(batch * 8 + chk) * HH + h] = part[0][h] + part[1][h] + part[2][h] + part[3][h];
}

// ---------------------------------------------------------------------------
// head: g[b] = mean; out[b] = relu(g@fw1+fb1)@fw2+fb2. Block = batch.
// ---------------------------------------------------------------------------
__global__ __launch_bounds__(256) void head_kernel(const float* __restrict__ pp,
                                                   const float* __restrict__ fw1,
                                                   const float* __restrict__ fb1,
                                                   const float* __restrict__ fw2,
                                                   const float* __restrict__ fb2,
                                                   float* __restrict__ out) {
    __shared__ float g[HH];
    __shared__ float tl[HH];
    const int b = blockIdx.x;
    const int tid = threadIdx.x;
    if (tid < HH) {
        float s = 0.f;
#pragma unroll
        for (int c = 0; c < 8; ++c) s += pp[(b * 8 + c) * HH + tid];
        g[tid] = s * (1.f / NN);
    }
    __syncthreads();
    if (tid < HH) {
        float a = fb1[tid];
#pragma unroll
        for (int l = 0; l < HH; ++l) a = fmaf(g[l], fw1[l * HH + tid], a);
        tl[tid] = fmaxf(a, 0.f);
    }
    __syncthreads();
    if (tid < OUTC) {
        float o = fb2[tid];
#pragma unroll
        for (int l = 0; l < HH; ++l) o = fmaf(tl[l], fw2[l * OUTC + tid], o);
        out[(long)b * OUTC + tid] = o;
    }
}

// ---------------------------------------------------------------------------
extern "C" void kernel_launch(void* const* d_in, const int* in_sizes, int n_in,
                              void* d_out, int out_size, void* d_ws, size_t ws_size,
                              hipStream_t stream) {
    const float* x    = (const float*)d_in[0];
    const float* w1_0 = (const float*)d_in[1];
    const float* b1_0 = (const float*)d_in[2];
    const float* wo_0 = (const float*)d_in[3];
    const float* bo_0 = (const float*)d_in[4];
    const float* w1_1 = (const float*)d_in[5];
    const float* b1_1 = (const float*)d_in[6];
    const float* wo_1 = (const float*)d_in[7];
    const float* bo_1 = (const float*)d_in[8];
    const float* w1_2 = (const float*)d_in[9];
    const float* b1_2 = (const float*)d_in[10];
    const float* wo_2 = (const float*)d_in[11];
    const float* bo_2 = (const float*)d_in[12];
    const float* fw1  = (const float*)d_in[13];
    const float* fb1  = (const float*)d_in[14];
    const float* fw2  = (const float*)d_in[15];
    const float* fb2  = (const float*)d_in[16];
    float* out = (float*)d_out;

    // workspace layout (floats)
    float* featA = (float*)d_ws;
    float* featB = featA + (long)BN * HH;
    float* Pb    = featB + (long)BN * HH;
    float* Qb    = Pb + (long)BN * HH;
    float* sqb   = Qb + (long)BN * HH;
    unsigned short* idx32 = (unsigned short*)(sqb + BN);     // BN x 32 u16
    float* ppb   = (float*)(idx32 + (long)BN * 32);          // 32 x 8 x 64

    // bf16 feature mirrors alias the OPPOSITE feature buffer (consumed by the
    // filter before rescore_gather rewrites that buffer)
    __bf16* fbf1 = (__bf16*)featB;   // layer 1 (featB rewritten after filter)
    __bf16* fbf2 = (__bf16*)featA;   // layer 2 (featA rewritten after filter)

    // ---- layer 0 (D=3, exact fp32 kNN) ----
    prep3_kernel<<<BN / 4, 256, 0, stream>>>(x, w1_0, b1_0, sqb, Pb, Qb);
    knn3_filter_kernel<<<BB * 32, 256, 0, stream>>>(x, sqb, idx32);
    rescore_gather_kernel<3><<<BN / 8, 256, 0, stream>>>(x, sqb, idx32, Pb, Qb, wo_0, bo_0, featA);

    // ---- layer 1 (D=64) ----
    prep64_kernel<<<BN / 64, 256, 0, stream>>>(featA, w1_1, b1_1, fbf1, sqb, Pb, Qb);
    knn_filter_kernel<<<BB * 32, 256, 0, stream>>>(fbf1, sqb, idx32);
    rescore_gather_kernel<64><<<BN / 8, 256, 0, stream>>>(featA, sqb, idx32, Pb, Qb, wo_1, bo_1, featB);

    // ---- layer 2 (D=64) ----
    prep64_kernel<<<BN / 64, 256, 0, stream>>>(featB, w1_2, b1_2, fbf2, sqb, Pb, Qb);
    knn_filter_kernel<<<BB * 32, 256, 0, stream>>>(fbf2, sqb, idx32);
    rescore_gather_kernel<64><<<BN / 8, 256, 0, stream>>>(featB, sqb, idx32, Pb, Qb, wo_2, bo_2, featA);

    // ---- pool + head ----
    pool_partial_kernel<<<BB * 8, 256, 0, stream>>>(featA, ppb);
    head_kernel<<<BB, 256, 0, stream>>>(ppb, fw1, fb1, fw2, fb2, out);
}

// Round 7
// 522.753 us; speedup vs baseline: 1.2994x; 1.2760x over previous
//
#include <hip/hip_runtime.h>

// Problem constants
#define BB 32
#define NN 2048
#define FF 3
#define HH 64
#define OUTC 128
#define KK 16
#define BN (BB * NN)   // 65536 points

typedef __attribute__((ext_vector_type(8))) __bf16 bf16x8;
typedef __attribute__((ext_vector_type(4))) float f32x4;

// Pack d2 + candidate index into one sortable u32:
// high 21 bits = monotone(float d2) truncated, low 11 bits = idx (NN=2^11).
__device__ __forceinline__ unsigned int packkey(float d2, unsigned int m) {
    unsigned int bb = __builtin_bit_cast(unsigned int, d2);
    unsigned int msk = (unsigned int)((int)bb >> 31);
    unsigned int srt = bb ^ (msk | 0x80000000u);
    return (srt & 0xFFFFF800u) | m;
}

// Full-precision sortable key: 32-bit monotone(f32) << 11 | idx. Lexicographic
// (d2, j) order in a single u64 compare — exact, tie-break on smaller index.
__device__ __forceinline__ unsigned long long pack64(float d2, unsigned int j) {
    unsigned int bb = __builtin_bit_cast(unsigned int, d2);
    unsigned int msk = (unsigned int)((int)bb >> 31);
    unsigned int srt = bb ^ (msk | 0x80000000u);
    return ((unsigned long long)srt << 11) | j;
}

__device__ __forceinline__ void ce(unsigned int& a, unsigned int& b) {
    unsigned int lo = a < b ? a : b;
    unsigned int hi = a < b ? b : a;
    a = lo; b = hi;
}

// Sort 16 keys ascending — Batcher odd-even mergesort (63 CE, branchless).
__device__ __forceinline__ void sort16(unsigned int k[16]) {
#pragma unroll
    for (int p = 1; p < 16; p <<= 1)
#pragma unroll
        for (int q = p; q >= 1; q >>= 1)
#pragma unroll
            for (int j = q % p; j + q < 16; j += 2 * q)
#pragma unroll
                for (int i = 0; i < q; ++i) {
                    int x = i + j, y = i + j + q;
                    if (y < 16 && (x / (2 * p) == y / (2 * p))) ce(k[x], k[y]);
                }
}

// keys (sorted asc) <- lowest-16 of union(keys, nk), nk sorted asc.
__device__ __forceinline__ void merge16(unsigned int keys[16], const unsigned int nk[16]) {
    unsigned int t[16];
#pragma unroll
    for (int i = 0; i < 16; ++i) {
        unsigned int b = nk[15 - i];
        t[i] = keys[i] < b ? keys[i] : b;
    }
#pragma unroll
    for (int d = 8; d >= 1; d >>= 1)
#pragma unroll
        for (int i = 0; i < 16; ++i)
            if ((i & d) == 0) ce(t[i], t[i ^ d]);
#pragma unroll
    for (int i = 0; i < 16; ++i) keys[i] = t[i];
}

__device__ __forceinline__ void load16(unsigned int dst[16], const unsigned int* __restrict__ src) {
#pragma unroll
    for (int q = 0; q < 4; ++q) {
        uint4 v = ((const uint4*)src)[q];
        dst[4 * q] = v.x; dst[4 * q + 1] = v.y;
        dst[4 * q + 2] = v.z; dst[4 * q + 3] = v.w;
    }
}

// ---------------------------------------------------------------------------
// prep3 (layer 0): sq + P/Q from x (D=3). Wave = one row (64 h-lanes).
// ---------------------------------------------------------------------------
__global__ __launch_bounds__(256) void prep3_kernel(const float* __restrict__ x,
                                                    const float* __restrict__ w1,
                                                    const float* __restrict__ b1,
                                                    float* __restrict__ sqo,
                                                    float* __restrict__ P,
                                                    float* __restrict__ Q) {
    const int tid = threadIdx.x;
    const int h = tid & 63;
    const int pl = tid >> 6;
    const long p = (long)blockIdx.x * 4 + pl;
    const float* fp = x + p * 3;
    const float f0 = fp[0], f1 = fp[1], f2 = fp[2];
    if (h == 0) sqo[p] = f0 * f0 + f1 * f1 + f2 * f2;
    float accp = 0.f, accq = 0.f;
    const float fv[3] = {f0, f1, f2};
#pragma unroll
    for (int d = 0; d < 3; ++d) {
        float wa = w1[d * HH + h];
        float wb = w1[(3 + d) * HH + h];
        accp = fmaf(fv[d], wa - wb, accp);
        accq = fmaf(fv[d], wb, accq);
    }
    P[p * HH + h] = accp + b1[h];
    Q[p * HH + h] = accq;
}

// ---------------------------------------------------------------------------
// prep64 (layers 1,2): fused bf16-convert + sq + P/Q. Block = 64 rows.
// ---------------------------------------------------------------------------
__global__ __launch_bounds__(256) void prep64_kernel(const float* __restrict__ feat,
                                                     const float* __restrict__ w1,
                                                     const float* __restrict__ b1,
                                                     __bf16* __restrict__ fbf,
                                                     float* __restrict__ sqo,
                                                     float* __restrict__ P,
                                                     float* __restrict__ Q) {
    __shared__ float rows[64 * HH];   // 16 KB
    const int tid = threadIdx.x;
    const int h = tid & 63;
    const int wv = tid >> 6;
    const long row0 = (long)blockIdx.x * 64;

    // loop-invariant weights -> VGPRs (coalesced, L1-resident after block 0)
    float wdiff[64], wbv[64];
#pragma unroll
    for (int d = 0; d < 64; ++d) {
        float wa = w1[d * HH + h];
        float wb_ = w1[(HH + d) * HH + h];
        wdiff[d] = wa - wb_;
        wbv[d] = wb_;
    }
    const float bv = b1[h];

    // stage 64 rows (coalesced float4)
    {
        const float4* src = (const float4*)(feat + row0 * HH);
        float4* dst = (float4*)rows;
#pragma unroll
        for (int i = 0; i < 4; ++i) dst[tid + 256 * i] = src[tid + 256 * i];
    }
    __syncthreads();

    // each wave handles 16 rows
    for (int r = wv * 16; r < wv * 16 + 16; ++r) {
        const long p = row0 + r;
        // transpose read (stride-1 per lane): bf16 convert + sq reduce
        float fvh = rows[r * HH + h];
        fbf[p * HH + h] = (__bf16)fvh;
        float s = fvh * fvh;
        s += __shfl_xor(s, 1);
        s += __shfl_xor(s, 2);
        s += __shfl_xor(s, 4);
        s += __shfl_xor(s, 8);
        s += __shfl_xor(s, 16);
        s += __shfl_xor(s, 32);
        if (h == 0) sqo[p] = s;

        float ap0 = 0.f, ap1 = 0.f, aq0 = 0.f, aq1 = 0.f;
#pragma unroll
        for (int d4 = 0; d4 < 16; ++d4) {
            float4 fv = *(const float4*)&rows[r * HH + d4 * 4];   // uniform -> broadcast
            ap0 = fmaf(fv.x, wdiff[4 * d4 + 0], ap0);
            aq0 = fmaf(fv.x, wbv[4 * d4 + 0], aq0);
            ap1 = fmaf(fv.y, wdiff[4 * d4 + 1], ap1);
            aq1 = fmaf(fv.y, wbv[4 * d4 + 1], aq1);
            ap0 = fmaf(fv.z, wdiff[4 * d4 + 2], ap0);
            aq0 = fmaf(fv.z, wbv[4 * d4 + 2], aq0);
            ap1 = fmaf(fv.w, wdiff[4 * d4 + 3], ap1);
            aq1 = fmaf(fv.w, wbv[4 * d4 + 3], aq1);
        }
        P[p * HH + h] = (ap0 + ap1) + bv;
        Q[p * HH + h] = aq0 + aq1;
    }
}

// ---------------------------------------------------------------------------
// Layer-0 kNN filter (D=3): CAND-SPLIT r4 structure. Block = 64 rows x 1024
// cands (half). Two-barrier staged tile + register prefetch (36-48 VGPR),
// interleaved slot partition (zero bank conflicts). Grid doubles -> 8
// blocks/CU (was 4, grid-limited 30% occupancy). Epilogue: exact sorted
// top-16 of the half via 3 chained merge16s; block writes its 16 into
// idx32[row*32 + half*16]. Union over halves covers the global top-16.
// ---------------------------------------------------------------------------
__global__ __launch_bounds__(256) void knn3_filter_kernel(const float* __restrict__ x,
                                                          const float* __restrict__ sq,
                                                          unsigned short* __restrict__ idx32) {
    __shared__ float4 lds_c[256];
    __shared__ unsigned int Km[64 * 68];
    const int tid = threadIdx.x;
    // batch->XCD pinning: blocks with blockIdx%8==x land on XCD x (heuristic)
    const int xcd = blockIdx.x & 7;
    const int ii = blockIdx.x >> 3;          // 0..255
    const int b = xcd + 8 * (ii >> 6);       // 4 batches per XCD
    const int sub = ii & 63;
    const int rg = sub >> 1;                 // 0..31 row-groups of 64
    const int half = sub & 1;                // candidate half
    const int cbase0 = half * 1024;
    const long pbase = (long)b * NN;
    const int r = tid >> 2, slot = tid & 3;
    const int row = rg * 64 + r;

    const float* rp = x + (pbase + row) * 3;
    const float xr0 = rp[0], xr1 = rp[1], xr2 = rp[2];

    unsigned int keys[KK];
#pragma unroll
    for (int j = 0; j < KK; ++j) keys[j] = 0xFFFFFFFFu;

    // preload tile 0
    float c0, c1, c2, c3;
    {
        const float* cp = x + (pbase + cbase0 + tid) * 3;
        c0 = cp[0]; c1 = cp[1]; c2 = cp[2]; c3 = sq[pbase + cbase0 + tid];
    }

    for (int t = 0; t < 4; ++t) {             // 4 tiles of 256 = the half
        __syncthreads();                      // prev selection done reading lds_c
        lds_c[tid] = make_float4(c0, c1, c2, c3);
        __syncthreads();                      // tile ready
        if (t < 3) {                          // prefetch next tile (hidden by selection)
            const int m = cbase0 + (t + 1) * 256 + tid;
            const float* cp = x + (pbase + m) * 3;
            c0 = cp[0]; c1 = cp[1]; c2 = cp[2]; c3 = sq[pbase + m];
        }
        // selection over interleaved candidates: slot s -> cands 4*k + s
#pragma unroll
        for (int bb = 0; bb < 4; ++bb) {
            unsigned int nk[16];
#pragma unroll
            for (int cc = 0; cc < 16; ++cc) {
                const int li = bb * 64 + cc * 4 + slot;
                float4 v = lds_c[li];
                float dot = fmaf(xr0, v.x, fmaf(xr1, v.y, xr2 * v.z));
                float d2 = fmaf(-2.0f, dot, v.w);   // sq_row dropped (rank-invariant)
                nk[cc] = packkey(d2, (unsigned int)(cbase0 + t * 256 + li));
            }
            sort16(nk);
            merge16(keys, nk);
        }
    }

    // epilogue: exact top-16 of the half = merge of 4 exact slot lists
    {
        uint4* kw = (uint4*)&Km[r * 68 + slot * 16];
#pragma unroll
        for (int q = 0; q < 4; ++q)
            kw[q] = make_uint4(keys[4 * q], keys[4 * q + 1], keys[4 * q + 2], keys[4 * q + 3]);
    }
    __syncthreads();
    if (slot == 0) {
        unsigned int m1[16], m2[16], tmp[16];
        load16(m1, &Km[r * 68]);
        load16(tmp, &Km[r * 68 + 16]);
        merge16(m1, tmp);
        load16(m2, &Km[r * 68 + 32]);
        load16(tmp, &Km[r * 68 + 48]);
        merge16(m2, tmp);
        merge16(m1, m2);                      // sorted top-16 of the half
        unsigned short ms[16];
#pragma unroll
        for (int j = 0; j < 16; ++j) ms[j] = (unsigned short)(m1[j] & 0x7FFu);
        uint4* op = (uint4*)(idx32 + ((pbase + row) * 32 + half * 16));
        op[0] = ((const uint4*)ms)[0];
        op[1] = ((const uint4*)ms)[1];
    }
}

// ---------------------------------------------------------------------------
// bf16-MFMA filter (D=64): CAND-SPLIT r4 structure. Block = 64 rows x 1024
// cands (half); 16 tiles of 64, LDS double-buffered, register prefetch,
// single barrier/tile (r4's proven 85µs/full shape; r6 lesson: register
// dbuf spills through the sort). Grid doubles -> 8 blocks/CU. Epilogue:
// exact sorted top-16 of the half; writes idx32[row*32 + half*16].
// ---------------------------------------------------------------------------
#define APAD 72   // LDS row stride (bf16 elems); 2-way bank alias (free)
#define DPAD 68   // key staging stride (u32), epilogue only

__global__ __launch_bounds__(256) void knn_filter_kernel(const __bf16* __restrict__ fbf,
                                                         const float* __restrict__ sq,
                                                         unsigned short* __restrict__ idx32) {
    // two cand-tile buffers (2 x 64 x APAD bf16 = 18432 B); reused as key
    // staging (64*DPAD*4 = 17408 B) in the epilogue.
    __shared__ __align__(16) unsigned char smem[2 * 64 * APAD * 2];
    __shared__ __align__(16) float SqD[2 * 64];

    const int tid = threadIdx.x;
    const int xcd = blockIdx.x & 7;
    const int ii = blockIdx.x >> 3;          // 0..255
    const int b = xcd + 8 * (ii >> 6);       // 4 batches per XCD
    const int sub = ii & 63;
    const int rg = sub >> 1;                 // 0..31 row-groups of 64
    const int half = sub & 1;                // candidate half
    const int cbase0 = half * 1024;
    const long pbase = (long)b * NN;
    const int row0 = rg * 64;
    const int ci = tid >> 2, ch = tid & 3;   // staging: cand ci, 16-dim chunk ch
    const int wv = tid >> 6, ln = tid & 63;
    const int n16 = ln & 15, quad = ln >> 4;

    // row fragments: load once, direct from global (L2-resident, 2x16B/lane)
    bf16x8 rf0, rf1;
    {
        const __bf16* rp = fbf + (pbase + row0 + wv * 16 + n16) * 64 + quad * 8;
        rf0 = *(const bf16x8*)rp;
        rf1 = *(const bf16x8*)(rp + 32);
    }

    unsigned int keys[KK];
#pragma unroll
    for (int j = 0; j < KK; ++j) keys[j] = 0xFFFFFFFFu;

    // preload tile 0 into registers
    uint4 pv0, pv1;
    float psq;
    {
        const __bf16* src = fbf + (pbase + cbase0 + ci) * 64 + ch * 16;
        pv0 = *(const uint4*)src;
        pv1 = *(const uint4*)(src + 8);
        psq = (tid < 64) ? sq[pbase + cbase0 + tid] : 0.f;
    }
    // write tile 0 -> buffer 0
    {
        __bf16* B0 = (__bf16*)smem;
        *(uint4*)&B0[ci * APAD + ch * 16] = pv0;
        *(uint4*)&B0[ci * APAD + ch * 16 + 8] = pv1;
        if (tid < 64) SqD[tid] = psq;
    }
    __syncthreads();

    for (int t = 0; t < 16; ++t) {            // 16 tiles of 64 = the half
        const int cur = t & 1;
        const __bf16* Bc = (const __bf16*)smem + cur * 64 * APAD;
        const float* Sc = SqD + cur * 64;

        // issue prefetch of tile t+1 (latency hidden by MFMA + selection)
        if (t < 15) {
            const __bf16* src = fbf + (pbase + cbase0 + (long)(t + 1) * 64 + ci) * 64 + ch * 16;
            pv0 = *(const uint4*)src;
            pv1 = *(const uint4*)(src + 8);
            if (tid < 64) psq = sq[pbase + cbase0 + (t + 1) * 64 + tid];
        }

        // MFMA phase: D[cand][row] -> lane gets 16 cands of its own row
        unsigned int nk[16];
#pragma unroll
        for (int ct = 0; ct < 4; ++ct) {
            const __bf16* cp = &Bc[(ct * 16 + n16) * APAD + quad * 8];
            bf16x8 cf0 = *(const bf16x8*)cp;
            bf16x8 cf1 = *(const bf16x8*)(cp + 32);
            f32x4 acc = {0.f, 0.f, 0.f, 0.f};
            acc = __builtin_amdgcn_mfma_f32_16x16x32_bf16(cf0, rf0, acc, 0, 0, 0);
            acc = __builtin_amdgcn_mfma_f32_16x16x32_bf16(cf1, rf1, acc, 0, 0, 0);
            f32x4 sv = *(const f32x4*)&Sc[ct * 16 + quad * 4];
            const unsigned int mb = (unsigned int)(cbase0 + t * 64 + ct * 16 + quad * 4);
#pragma unroll
            for (int rr = 0; rr < 4; ++rr)
                nk[ct * 4 + rr] = packkey(fmaf(-2.0f, acc[rr], sv[rr]), mb + rr);
        }

        // write prefetched tile to the other buffer (WAR-safe: its readers
        // finished before the barrier at end of iteration t-1)
        if (t < 15) {
            __bf16* Bn = (__bf16*)smem + (cur ^ 1) * 64 * APAD;
            *(uint4*)&Bn[ci * APAD + ch * 16] = pv0;
            *(uint4*)&Bn[ci * APAD + ch * 16 + 8] = pv1;
            if (tid < 64) SqD[(cur ^ 1) * 64 + tid] = psq;
        }

        // selection: pure-register sort + merge into persistent top-16
        sort16(nk);
        merge16(keys, nk);

        __syncthreads();   // single barrier: tile t+1 ready, tile t reads done
    }

    // epilogue: exact top-16 of the half = merge of 4 exact slot lists
    unsigned int* stg = (unsigned int*)smem;   // aliases Bb (safe after barrier)
    {
        uint4* kw = (uint4*)&stg[(wv * 16 + n16) * DPAD + quad * 16];
#pragma unroll
        for (int q = 0; q < 4; ++q)
            kw[q] = make_uint4(keys[4 * q], keys[4 * q + 1], keys[4 * q + 2], keys[4 * q + 3]);
    }
    __syncthreads();
    const int r = tid >> 2, slot = tid & 3;
    if (slot == 0) {
        unsigned int m1[16], m2[16], tmp[16];
        load16(m1, &stg[r * DPAD]);
        load16(tmp, &stg[r * DPAD + 16]);
        merge16(m1, tmp);
        load16(m2, &stg[r * DPAD + 32]);
        load16(tmp, &stg[r * DPAD + 48]);
        merge16(m2, tmp);
        merge16(m1, m2);                      // sorted top-16 of the half
        unsigned short ms[16];
#pragma unroll
        for (int j = 0; j < 16; ++j) ms[j] = (unsigned short)(m1[j] & 0x7FFu);
        uint4* op = (uint4*)(idx32 + ((pbase + row0 + r) * 32 + half * 16));
        op[0] = ((const uint4*)ms)[0];
        op[1] = ((const uint4*)ms)[1];
    }
}

// ---------------------------------------------------------------------------
// Fused rescore + gather + edge-MLP — WAVE-AUTONOMOUS version.
// Each wave owns 2 rows end-to-end: no __syncthreads anywhere; cross-lane
// data moves via __shfl and wave-local LDS regions fenced with
// s_waitcnt lgkmcnt(0) + sched_barrier(0).
// Exact fp32 selection preserved via 43-bit packed (d2,j) u64 keys.
// ---------------------------------------------------------------------------
template <int D>
__global__ __launch_bounds__(256) void rescore_gather_kernel(const float* __restrict__ feat,
                                                             const float* __restrict__ sq,
                                                             const unsigned short* __restrict__ idx32,
                                                             const float* __restrict__ P,
                                                             const float* __restrict__ Q,
                                                             const float* __restrict__ wo,
                                                             const float* __restrict__ bo,
                                                             float* __restrict__ outf) {
    __shared__ unsigned long long ScK[4][2][32];   // per-wave packed (d2,j) keys
    __shared__ int Li[4][2][KK];                   // per-wave selected indices
    __shared__ float Rl[4][2][HH];                 // per-wave relu-mean

    const int tid = threadIdx.x;
    const int wv = tid >> 6, ln = tid & 63;
    const int rw = ln >> 5, c = ln & 31;
    // batch->XCD pinning: each XCD's L2 sees only 4 batches' gather set
    const int xcd = blockIdx.x & 7;
    const int ii = blockIdx.x >> 3;            // 0..1023
    const int batch = xcd + 8 * (ii >> 8);     // 4 batches per XCD
    const int rb = ii & 255;
    const long pbase = (long)batch * NN;
    const long pblk = pbase + (long)rb * 8;
    const int rA = wv * 2;                     // wave's first local row
    const long prow = pblk + rA + rw;          // lane's owned (row) for idx/rank

    // own candidate: lane (rw, c) owns cand c of row rA+rw
    const int jown = (int)idx32[prow * 32 + c];
    const float sqown = sq[pbase + jown];

    if constexpr (D == 64) {
        // quad-cooperative fp32 rescore: 4 lanes per cand, 64B granules
        const int cg = ln >> 2, e = ln & 3;
#pragma unroll
        for (int rr = 0; rr < 2; ++rr) {
            const float* rbase = feat + (pblk + rA + rr) * 64;
            const float4 rv0 = *(const float4*)(rbase + 0 * 16 + e * 4);
            const float4 rv1 = *(const float4*)(rbase + 1 * 16 + e * 4);
            const float4 rv2 = *(const float4*)(rbase + 2 * 16 + e * 4);
            const float4 rv3 = *(const float4*)(rbase + 3 * 16 + e * 4);
#pragma unroll
            for (int pp = 0; pp < 2; ++pp) {
                const int srcl = rr * 32 + pp * 16 + cg;
                const int jq = __shfl(jown, srcl);
                const float sqc = __shfl(sqown, srcl);
                const float* cb = feat + (pbase + jq) * 64;
                const float4 cv0 = *(const float4*)(cb + 0 * 16 + e * 4);
                const float4 cv1 = *(const float4*)(cb + 1 * 16 + e * 4);
                const float4 cv2 = *(const float4*)(cb + 2 * 16 + e * 4);
                const float4 cv3 = *(const float4*)(cb + 3 * 16 + e * 4);
                float part = 0.f;
                part = fmaf(rv0.x, cv0.x, part); part = fmaf(rv0.y, cv0.y, part);
                part = fmaf(rv0.z, cv0.z, part); part = fmaf(rv0.w, cv0.w, part);
                part = fmaf(rv1.x, cv1.x, part); part = fmaf(rv1.y, cv1.y, part);
                part = fmaf(rv1.z, cv1.z, part); part = fmaf(rv1.w, cv1.w, part);
                part = fmaf(rv2.x, cv2.x, part); part = fmaf(rv2.y, cv2.y, part);
                part = fmaf(rv2.z, cv2.z, part); part = fmaf(rv2.w, cv2.w, part);
                part = fmaf(rv3.x, cv3.x, part); part = fmaf(rv3.y, cv3.y, part);
                part = fmaf(rv3.z, cv3.z, part); part = fmaf(rv3.w, cv3.w, part);
                part += __shfl_xor(part, 1);
                part += __shfl_xor(part, 2);
                if (e == 0)
                    ScK[wv][rr][pp * 16 + cg] =
                        pack64(fmaf(-2.0f, part, sqc), (unsigned int)jq);
            }
        }
    } else {
        // D==3: lane computes its own cand's exact d2 directly
        const float* rp = feat + prow * 3;
        const float xr0 = rp[0], xr1 = rp[1], xr2 = rp[2];
        const float* cp = feat + (pbase + jown) * 3;
        const float dot = fmaf(xr0, cp[0], fmaf(xr1, cp[1], xr2 * cp[2]));
        ScK[wv][rw][c] = pack64(fmaf(-2.0f, dot, sqown), (unsigned int)jown);
    }
    asm volatile("s_waitcnt lgkmcnt(0)" ::: "memory");
    __builtin_amdgcn_sched_barrier(0);

    // rank: exact lexicographic (d2, j) via single u64 compare, LDS broadcast
    {
        const unsigned long long mykey = ScK[wv][rw][c];
        int rank = 0;
#pragma unroll
        for (int m = 0; m < 32; ++m)
            rank += (ScK[wv][rw][m] < mykey) ? 1 : 0;
        if (rank < KK) Li[wv][rw][rank] = (int)(mykey & 0x7FFu);
    }
    asm volatile("s_waitcnt lgkmcnt(0)" ::: "memory");
    __builtin_amdgcn_sched_barrier(0);

    // Phase 2: Q-gather + relu-mean + wo matmul; lane = h, 2 rows per wave
    const int h = ln;
    const long pA = pblk + rA;
    const float PvA = P[pA * HH + h];
    const float PvB = P[(pA + 1) * HH + h];
    float accA = 0.f, accB = 0.f;
#pragma unroll
    for (int kq = 0; kq < 4; ++kq) {
        const int4 a4 = *(const int4*)&Li[wv][0][kq * 4];   // uniform -> broadcast
        const int4 b4 = *(const int4*)&Li[wv][1][kq * 4];
        accA += fmaxf(PvA + Q[(pbase + a4.x) * HH + h], 0.f);
        accA += fmaxf(PvA + Q[(pbase + a4.y) * HH + h], 0.f);
        accA += fmaxf(PvA + Q[(pbase + a4.z) * HH + h], 0.f);
        accA += fmaxf(PvA + Q[(pbase + a4.w) * HH + h], 0.f);
        accB += fmaxf(PvB + Q[(pbase + b4.x) * HH + h], 0.f);
        accB += fmaxf(PvB + Q[(pbase + b4.y) * HH + h], 0.f);
        accB += fmaxf(PvB + Q[(pbase + b4.z) * HH + h], 0.f);
        accB += fmaxf(PvB + Q[(pbase + b4.w) * HH + h], 0.f);
    }
    Rl[wv][0][h] = accA * (1.f / KK);
    Rl[wv][1][h] = accB * (1.f / KK);
    asm volatile("s_waitcnt lgkmcnt(0)" ::: "memory");
    __builtin_amdgcn_sched_barrier(0);

    float oA = bo[h];
    float oB = oA;
#pragma unroll
    for (int l4 = 0; l4 < 16; ++l4) {
        const float4 ra = *(const float4*)&Rl[wv][0][l4 * 4];   // uniform broadcast
        const float4 rb4 = *(const float4*)&Rl[wv][1][l4 * 4];
        const float* wp = wo + (l4 * 4) * HH + h;               // L1-hot, shared A/B
        const float w0 = wp[0], w1 = wp[HH], w2 = wp[2 * HH], w3 = wp[3 * HH];
        oA = fmaf(ra.x, w0, oA);  oB = fmaf(rb4.x, w0, oB);
        oA = fmaf(ra.y, w1, oA);  oB = fmaf(rb4.y, w1, oB);
        oA = fmaf(ra.z, w2, oA);  oB = fmaf(rb4.z, w2, oB);
        oA = fmaf(ra.w, w3, oA);  oB = fmaf(rb4.w, w3, oB);
    }
    outf[pA * HH + h] = oA;
    outf[(pA + 1) * HH + h] = oB;
}

// ---------------------------------------------------------------------------
// pool partial: block = (batch, chunk of 8); sums 256 rows -> pp[batch][ch][64]
// ---------------------------------------------------------------------------
__global__ __launch_bounds__(256) void pool_partial_kernel(const float* __restrict__ feat,
                                                           float* __restrict__ pp) {
    __shared__ float part[4][HH];
    const int batch = blockIdx.x >> 3;
    const int chk = blockIdx.x & 7;
    const int tid = threadIdx.x;
    const int h = tid & 63;
    const int sub = tid >> 6;
    float s = 0.f;
    const float* fp = feat + ((long)batch * NN + chk * 256 + sub * 64) * HH + h;
    for (int n = 0; n < 64; ++n) s += fp[(long)n * HH];
    part[sub][h] = s;
    __syncthreads();
    if (tid < HH)
        pp[(batch * 8 + chk) * HH + h] = part[0][h] + part[1][h] + part[2][h] + part[3][h];
}

// ---------------------------------------------------------------------------
// head: g[b] = mean; out[b] = relu(g@fw1+fb1)@fw2+fb2. Block = batch.
// ---------------------------------------------------------------------------
__global__ __launch_bounds__(256) void head_kernel(const float* __restrict__ pp,
                                                   const float* __restrict__ fw1,
                                                   const float* __restrict__ fb1,
                                                   const float* __restrict__ fw2,
                                                   const float* __restrict__ fb2,
                                                   float* __restrict__ out) {
    __shared__ float g[HH];
    __shared__ float tl[HH];
    const int b = blockIdx.x;
    const int tid = threadIdx.x;
    if (tid < HH) {
        float s = 0.f;
#pragma unroll
        for (int c = 0; c < 8; ++c) s += pp[(b * 8 + c) * HH + tid];
        g[tid] = s * (1.f / NN);
    }
    __syncthreads();
    if (tid < HH) {
        float a = fb1[tid];
#pragma unroll
        for (int l = 0; l < HH; ++l) a = fmaf(g[l], fw1[l * HH + tid], a);
        tl[tid] = fmaxf(a, 0.f);
    }
    __syncthreads();
    if (tid < OUTC) {
        float o = fb2[tid];
#pragma unroll
        for (int l = 0; l < HH; ++l) o = fmaf(tl[l], fw2[l * OUTC + tid], o);
        out[(long)b * OUTC + tid] = o;
    }
}

// ---------------------------------------------------------------------------
extern "C" void kernel_launch(void* const* d_in, const int* in_sizes, int n_in,
                              void* d_out, int out_size, void* d_ws, size_t ws_size,
                              hipStream_t stream) {
    const float* x    = (const float*)d_in[0];
    const float* w1_0 = (const float*)d_in[1];
    const float* b1_0 = (const float*)d_in[2];
    const float* wo_0 = (const float*)d_in[3];
    const float* bo_0 = (const float*)d_in[4];
    const float* w1_1 = (const float*)d_in[5];
    const float* b1_1 = (const float*)d_in[6];
    const float* wo_1 = (const float*)d_in[7];
    const float* bo_1 = (const float*)d_in[8];
    const float* w1_2 = (const float*)d_in[9];
    const float* b1_2 = (const float*)d_in[10];
    const float* wo_2 = (const float*)d_in[11];
    const float* bo_2 = (const float*)d_in[12];
    const float* fw1  = (const float*)d_in[13];
    const float* fb1  = (const float*)d_in[14];
    const float* fw2  = (const float*)d_in[15];
    const float* fb2  = (const float*)d_in[16];
    float* out = (float*)d_out;

    // workspace layout (floats)
    float* featA = (float*)d_ws;
    float* featB = featA + (long)BN * HH;
    float* Pb    = featB + (long)BN * HH;
    float* Qb    = Pb + (long)BN * HH;
    float* sqb   = Qb + (long)BN * HH;
    unsigned short* idx32 = (unsigned short*)(sqb + BN);     // BN x 32 u16
    float* ppb   = (float*)(idx32 + (long)BN * 32);          // 32 x 8 x 64

    // bf16 feature mirrors alias the OPPOSITE feature buffer (consumed by the
    // filter before rescore_gather rewrites that buffer)
    __bf16* fbf1 = (__bf16*)featB;   // layer 1 (featB rewritten after filter)
    __bf16* fbf2 = (__bf16*)featA;   // layer 2 (featA rewritten after filter)

    // ---- layer 0 (D=3, exact fp32 kNN) ----
    prep3_kernel<<<BN / 4, 256, 0, stream>>>(x, w1_0, b1_0, sqb, Pb, Qb);
    knn3_filter_kernel<<<BB * 64, 256, 0, stream>>>(x, sqb, idx32);
    rescore_gather_kernel<3><<<BN / 8, 256, 0, stream>>>(x, sqb, idx32, Pb, Qb, wo_0, bo_0, featA);

    // ---- layer 1 (D=64) ----
    prep64_kernel<<<BN / 64, 256, 0, stream>>>(featA, w1_1, b1_1, fbf1, sqb, Pb, Qb);
    knn_filter_kernel<<<BB * 64, 256, 0, stream>>>(fbf1, sqb, idx32);
    rescore_gather_kernel<64><<<BN / 8, 256, 0, stream>>>(featA, sqb, idx32, Pb, Qb, wo_1, bo_1, featB);

    // ---- layer 2 (D=64) ----
    prep64_kernel<<<BN / 64, 256, 0, stream>>>(featB, w1_2, b1_2, fbf2, sqb, Pb, Qb);
    knn_filter_kernel<<<BB * 64, 256, 0, stream>>>(fbf2, sqb, idx32);
    rescore_gather_kernel<64><<<BN / 8, 256, 0, stream>>>(featB, sqb, idx32, Pb, Qb, wo_2, bo_2, featA);

    // ---- pool + head ----
    pool_partial_kernel<<<BB * 8, 256, 0, stream>>>(featA, ppb);
    head_kernel<<<BB, 256, 0, stream>>>(ppb, fw1, fb1, fw2, fb2, out);
}

// Round 8
// 499.945 us; speedup vs baseline: 1.3587x; 1.0456x over previous
//
#include <hip/hip_runtime.h>

// Problem constants
#define BB 32
#define NN 2048
#define FF 3
#define HH 64
#define OUTC 128
#define KK 16
#define BN (BB * NN)   // 65536 points

typedef __attribute__((ext_vector_type(8))) __bf16 bf16x8;
typedef __attribute__((ext_vector_type(4))) float f32x4;

// Pack d2 + candidate index into one sortable u32:
// high 21 bits = monotone(float d2) truncated, low 11 bits = idx (NN=2^11).
__device__ __forceinline__ unsigned int packkey(float d2, unsigned int m) {
    unsigned int bb = __builtin_bit_cast(unsigned int, d2);
    unsigned int msk = (unsigned int)((int)bb >> 31);
    unsigned int srt = bb ^ (msk | 0x80000000u);
    return (srt & 0xFFFFF800u) | m;
}

// Full-precision sortable key: 32-bit monotone(f32) << 11 | idx. Lexicographic
// (d2, j) order in a single u64 compare — exact, tie-break on smaller index.
__device__ __forceinline__ unsigned long long pack64(float d2, unsigned int j) {
    unsigned int bb = __builtin_bit_cast(unsigned int, d2);
    unsigned int msk = (unsigned int)((int)bb >> 31);
    unsigned int srt = bb ^ (msk | 0x80000000u);
    return ((unsigned long long)srt << 11) | j;
}

__device__ __forceinline__ void ce(unsigned int& a, unsigned int& b) {
    unsigned int lo = a < b ? a : b;
    unsigned int hi = a < b ? b : a;
    a = lo; b = hi;
}

// Sort 16 keys ascending — Batcher odd-even mergesort (63 CE, branchless).
__device__ __forceinline__ void sort16(unsigned int k[16]) {
#pragma unroll
    for (int p = 1; p < 16; p <<= 1)
#pragma unroll
        for (int q = p; q >= 1; q >>= 1)
#pragma unroll
            for (int j = q % p; j + q < 16; j += 2 * q)
#pragma unroll
                for (int i = 0; i < q; ++i) {
                    int x = i + j, y = i + j + q;
                    if (y < 16 && (x / (2 * p) == y / (2 * p))) ce(k[x], k[y]);
                }
}

// keys (sorted asc) <- lowest-16 of union(keys, nk), nk sorted asc.
__device__ __forceinline__ void merge16(unsigned int keys[16], const unsigned int nk[16]) {
    unsigned int t[16];
#pragma unroll
    for (int i = 0; i < 16; ++i) {
        unsigned int b = nk[15 - i];
        t[i] = keys[i] < b ? keys[i] : b;
    }
#pragma unroll
    for (int d = 8; d >= 1; d >>= 1)
#pragma unroll
        for (int i = 0; i < 16; ++i)
            if ((i & d) == 0) ce(t[i], t[i ^ d]);
#pragma unroll
    for (int i = 0; i < 16; ++i) keys[i] = t[i];
}

__device__ __forceinline__ void load16(unsigned int dst[16], const unsigned int* __restrict__ src) {
#pragma unroll
    for (int q = 0; q < 4; ++q) {
        uint4 v = ((const uint4*)src)[q];
        dst[4 * q] = v.x; dst[4 * q + 1] = v.y;
        dst[4 * q + 2] = v.z; dst[4 * q + 3] = v.w;
    }
}

// ---------------------------------------------------------------------------
// prep3 (layer 0): sq + P/Q from x (D=3). Wave = one row (64 h-lanes).
// ---------------------------------------------------------------------------
__global__ __launch_bounds__(256) void prep3_kernel(const float* __restrict__ x,
                                                    const float* __restrict__ w1,
                                                    const float* __restrict__ b1,
                                                    float* __restrict__ sqo,
                                                    float* __restrict__ P,
                                                    float* __restrict__ Q) {
    const int tid = threadIdx.x;
    const int h = tid & 63;
    const int pl = tid >> 6;
    const long p = (long)blockIdx.x * 4 + pl;
    const float* fp = x + p * 3;
    const float f0 = fp[0], f1 = fp[1], f2 = fp[2];
    if (h == 0) sqo[p] = f0 * f0 + f1 * f1 + f2 * f2;
    float accp = 0.f, accq = 0.f;
    const float fv[3] = {f0, f1, f2};
#pragma unroll
    for (int d = 0; d < 3; ++d) {
        float wa = w1[d * HH + h];
        float wb = w1[(3 + d) * HH + h];
        accp = fmaf(fv[d], wa - wb, accp);
        accq = fmaf(fv[d], wb, accq);
    }
    P[p * HH + h] = accp + b1[h];
    Q[p * HH + h] = accq;
}

// ---------------------------------------------------------------------------
// prep64 (layers 1,2): fused bf16-convert + sq + P/Q. Block = 64 rows.
// ---------------------------------------------------------------------------
__global__ __launch_bounds__(256) void prep64_kernel(const float* __restrict__ feat,
                                                     const float* __restrict__ w1,
                                                     const float* __restrict__ b1,
                                                     __bf16* __restrict__ fbf,
                                                     float* __restrict__ sqo,
                                                     float* __restrict__ P,
                                                     float* __restrict__ Q) {
    __shared__ float rows[64 * HH];   // 16 KB
    const int tid = threadIdx.x;
    const int h = tid & 63;
    const int wv = tid >> 6;
    const long row0 = (long)blockIdx.x * 64;

    // loop-invariant weights -> VGPRs (coalesced, L1-resident after block 0)
    float wdiff[64], wbv[64];
#pragma unroll
    for (int d = 0; d < 64; ++d) {
        float wa = w1[d * HH + h];
        float wb_ = w1[(HH + d) * HH + h];
        wdiff[d] = wa - wb_;
        wbv[d] = wb_;
    }
    const float bv = b1[h];

    // stage 64 rows (coalesced float4)
    {
        const float4* src = (const float4*)(feat + row0 * HH);
        float4* dst = (float4*)rows;
#pragma unroll
        for (int i = 0; i < 4; ++i) dst[tid + 256 * i] = src[tid + 256 * i];
    }
    __syncthreads();

    // each wave handles 16 rows
    for (int r = wv * 16; r < wv * 16 + 16; ++r) {
        const long p = row0 + r;
        // transpose read (stride-1 per lane): bf16 convert + sq reduce
        float fvh = rows[r * HH + h];
        fbf[p * HH + h] = (__bf16)fvh;
        float s = fvh * fvh;
        s += __shfl_xor(s, 1);
        s += __shfl_xor(s, 2);
        s += __shfl_xor(s, 4);
        s += __shfl_xor(s, 8);
        s += __shfl_xor(s, 16);
        s += __shfl_xor(s, 32);
        if (h == 0) sqo[p] = s;

        float ap0 = 0.f, ap1 = 0.f, aq0 = 0.f, aq1 = 0.f;
#pragma unroll
        for (int d4 = 0; d4 < 16; ++d4) {
            float4 fv = *(const float4*)&rows[r * HH + d4 * 4];   // uniform -> broadcast
            ap0 = fmaf(fv.x, wdiff[4 * d4 + 0], ap0);
            aq0 = fmaf(fv.x, wbv[4 * d4 + 0], aq0);
            ap1 = fmaf(fv.y, wdiff[4 * d4 + 1], ap1);
            aq1 = fmaf(fv.y, wbv[4 * d4 + 1], aq1);
            ap0 = fmaf(fv.z, wdiff[4 * d4 + 2], ap0);
            aq0 = fmaf(fv.z, wbv[4 * d4 + 2], aq0);
            ap1 = fmaf(fv.w, wdiff[4 * d4 + 3], ap1);
            aq1 = fmaf(fv.w, wbv[4 * d4 + 3], aq1);
        }
        P[p * HH + h] = (ap0 + ap1) + bv;
        Q[p * HH + h] = aq0 + aq1;
    }
}

// ---------------------------------------------------------------------------
// Layer-0 kNN filter (D=3): CAND-SPLIT structure (r7, measured 85µs @92%
// VALUBusy — at the issue floor for this algorithm). Unchanged.
// ---------------------------------------------------------------------------
__global__ __launch_bounds__(256) void knn3_filter_kernel(const float* __restrict__ x,
                                                          const float* __restrict__ sq,
                                                          unsigned short* __restrict__ idx32) {
    __shared__ float4 lds_c[256];
    __shared__ unsigned int Km[64 * 68];
    const int tid = threadIdx.x;
    const int xcd = blockIdx.x & 7;
    const int ii = blockIdx.x >> 3;          // 0..255
    const int b = xcd + 8 * (ii >> 6);       // 4 batches per XCD
    const int sub = ii & 63;
    const int rg = sub >> 1;                 // 0..31 row-groups of 64
    const int half = sub & 1;                // candidate half
    const int cbase0 = half * 1024;
    const long pbase = (long)b * NN;
    const int r = tid >> 2, slot = tid & 3;
    const int row = rg * 64 + r;

    const float* rp = x + (pbase + row) * 3;
    const float xr0 = rp[0], xr1 = rp[1], xr2 = rp[2];

    unsigned int keys[KK];
#pragma unroll
    for (int j = 0; j < KK; ++j) keys[j] = 0xFFFFFFFFu;

    // preload tile 0
    float c0, c1, c2, c3;
    {
        const float* cp = x + (pbase + cbase0 + tid) * 3;
        c0 = cp[0]; c1 = cp[1]; c2 = cp[2]; c3 = sq[pbase + cbase0 + tid];
    }

    for (int t = 0; t < 4; ++t) {             // 4 tiles of 256 = the half
        __syncthreads();                      // prev selection done reading lds_c
        lds_c[tid] = make_float4(c0, c1, c2, c3);
        __syncthreads();                      // tile ready
        if (t < 3) {                          // prefetch next tile (hidden by selection)
            const int m = cbase0 + (t + 1) * 256 + tid;
            const float* cp = x + (pbase + m) * 3;
            c0 = cp[0]; c1 = cp[1]; c2 = cp[2]; c3 = sq[pbase + m];
        }
        // selection over interleaved candidates: slot s -> cands 4*k + s
#pragma unroll
        for (int bb = 0; bb < 4; ++bb) {
            unsigned int nk[16];
#pragma unroll
            for (int cc = 0; cc < 16; ++cc) {
                const int li = bb * 64 + cc * 4 + slot;
                float4 v = lds_c[li];
                float dot = fmaf(xr0, v.x, fmaf(xr1, v.y, xr2 * v.z));
                float d2 = fmaf(-2.0f, dot, v.w);   // sq_row dropped (rank-invariant)
                nk[cc] = packkey(d2, (unsigned int)(cbase0 + t * 256 + li));
            }
            sort16(nk);
            merge16(keys, nk);
        }
    }

    // epilogue: exact top-16 of the half = merge of 4 exact slot lists
    {
        uint4* kw = (uint4*)&Km[r * 68 + slot * 16];
#pragma unroll
        for (int q = 0; q < 4; ++q)
            kw[q] = make_uint4(keys[4 * q], keys[4 * q + 1], keys[4 * q + 2], keys[4 * q + 3]);
    }
    __syncthreads();
    if (slot == 0) {
        unsigned int m1[16], m2[16], tmp[16];
        load16(m1, &Km[r * 68]);
        load16(tmp, &Km[r * 68 + 16]);
        merge16(m1, tmp);
        load16(m2, &Km[r * 68 + 32]);
        load16(tmp, &Km[r * 68 + 48]);
        merge16(m2, tmp);
        merge16(m1, m2);                      // sorted top-16 of the half
        unsigned short ms[16];
#pragma unroll
        for (int j = 0; j < 16; ++j) ms[j] = (unsigned short)(m1[j] & 0x7FFu);
        uint4* op = (uint4*)(idx32 + ((pbase + row) * 32 + half * 16));
        op[0] = ((const uint4*)ms)[0];
        op[1] = ((const uint4*)ms)[1];
    }
}

// ---------------------------------------------------------------------------
// bf16-MFMA filter (D=64): CAND-SPLIT structure (r7, measured 85µs @82-86%
// VALUBusy — at the issue floor for this algorithm). Unchanged.
// ---------------------------------------------------------------------------
#define APAD 72   // LDS row stride (bf16 elems); 2-way bank alias (free)
#define DPAD 68   // key staging stride (u32), epilogue only

__global__ __launch_bounds__(256) void knn_filter_kernel(const __bf16* __restrict__ fbf,
                                                         const float* __restrict__ sq,
                                                         unsigned short* __restrict__ idx32) {
    __shared__ __align__(16) unsigned char smem[2 * 64 * APAD * 2];
    __shared__ __align__(16) float SqD[2 * 64];

    const int tid = threadIdx.x;
    const int xcd = blockIdx.x & 7;
    const int ii = blockIdx.x >> 3;          // 0..255
    const int b = xcd + 8 * (ii >> 6);       // 4 batches per XCD
    const int sub = ii & 63;
    const int rg = sub >> 1;                 // 0..31 row-groups of 64
    const int half = sub & 1;                // candidate half
    const int cbase0 = half * 1024;
    const long pbase = (long)b * NN;
    const int row0 = rg * 64;
    const int ci = tid >> 2, ch = tid & 3;   // staging: cand ci, 16-dim chunk ch
    const int wv = tid >> 6, ln = tid & 63;
    const int n16 = ln & 15, quad = ln >> 4;

    // row fragments: load once, direct from global (L2-resident, 2x16B/lane)
    bf16x8 rf0, rf1;
    {
        const __bf16* rp = fbf + (pbase + row0 + wv * 16 + n16) * 64 + quad * 8;
        rf0 = *(const bf16x8*)rp;
        rf1 = *(const bf16x8*)(rp + 32);
    }

    unsigned int keys[KK];
#pragma unroll
    for (int j = 0; j < KK; ++j) keys[j] = 0xFFFFFFFFu;

    // preload tile 0 into registers
    uint4 pv0, pv1;
    float psq;
    {
        const __bf16* src = fbf + (pbase + cbase0 + ci) * 64 + ch * 16;
        pv0 = *(const uint4*)src;
        pv1 = *(const uint4*)(src + 8);
        psq = (tid < 64) ? sq[pbase + cbase0 + tid] : 0.f;
    }
    // write tile 0 -> buffer 0
    {
        __bf16* B0 = (__bf16*)smem;
        *(uint4*)&B0[ci * APAD + ch * 16] = pv0;
        *(uint4*)&B0[ci * APAD + ch * 16 + 8] = pv1;
        if (tid < 64) SqD[tid] = psq;
    }
    __syncthreads();

    for (int t = 0; t < 16; ++t) {            // 16 tiles of 64 = the half
        const int cur = t & 1;
        const __bf16* Bc = (const __bf16*)smem + cur * 64 * APAD;
        const float* Sc = SqD + cur * 64;

        // issue prefetch of tile t+1 (latency hidden by MFMA + selection)
        if (t < 15) {
            const __bf16* src = fbf + (pbase + cbase0 + (long)(t + 1) * 64 + ci) * 64 + ch * 16;
            pv0 = *(const uint4*)src;
            pv1 = *(const uint4*)(src + 8);
            if (tid < 64) psq = sq[pbase + cbase0 + (t + 1) * 64 + tid];
        }

        // MFMA phase: D[cand][row] -> lane gets 16 cands of its own row
        unsigned int nk[16];
#pragma unroll
        for (int ct = 0; ct < 4; ++ct) {
            const __bf16* cp = &Bc[(ct * 16 + n16) * APAD + quad * 8];
            bf16x8 cf0 = *(const bf16x8*)cp;
            bf16x8 cf1 = *(const bf16x8*)(cp + 32);
            f32x4 acc = {0.f, 0.f, 0.f, 0.f};
            acc = __builtin_amdgcn_mfma_f32_16x16x32_bf16(cf0, rf0, acc, 0, 0, 0);
            acc = __builtin_amdgcn_mfma_f32_16x16x32_bf16(cf1, rf1, acc, 0, 0, 0);
            f32x4 sv = *(const f32x4*)&Sc[ct * 16 + quad * 4];
            const unsigned int mb = (unsigned int)(cbase0 + t * 64 + ct * 16 + quad * 4);
#pragma unroll
            for (int rr = 0; rr < 4; ++rr)
                nk[ct * 4 + rr] = packkey(fmaf(-2.0f, acc[rr], sv[rr]), mb + rr);
        }

        // write prefetched tile to the other buffer (WAR-safe: its readers
        // finished before the barrier at end of iteration t-1)
        if (t < 15) {
            __bf16* Bn = (__bf16*)smem + (cur ^ 1) * 64 * APAD;
            *(uint4*)&Bn[ci * APAD + ch * 16] = pv0;
            *(uint4*)&Bn[ci * APAD + ch * 16 + 8] = pv1;
            if (tid < 64) SqD[(cur ^ 1) * 64 + tid] = psq;
        }

        // selection: pure-register sort + merge into persistent top-16
        sort16(nk);
        merge16(keys, nk);

        __syncthreads();   // single barrier: tile t+1 ready, tile t reads done
    }

    // epilogue: exact top-16 of the half = merge of 4 exact slot lists
    unsigned int* stg = (unsigned int*)smem;   // aliases Bb (safe after barrier)
    {
        uint4* kw = (uint4*)&stg[(wv * 16 + n16) * DPAD + quad * 16];
#pragma unroll
        for (int q = 0; q < 4; ++q)
            kw[q] = make_uint4(keys[4 * q], keys[4 * q + 1], keys[4 * q + 2], keys[4 * q + 3]);
    }
    __syncthreads();
    const int r = tid >> 2, slot = tid & 3;
    if (slot == 0) {
        unsigned int m1[16], m2[16], tmp[16];
        load16(m1, &stg[r * DPAD]);
        load16(tmp, &stg[r * DPAD + 16]);
        merge16(m1, tmp);
        load16(m2, &stg[r * DPAD + 32]);
        load16(tmp, &stg[r * DPAD + 48]);
        merge16(m2, tmp);
        merge16(m1, m2);                      // sorted top-16 of the half
        unsigned short ms[16];
#pragma unroll
        for (int j = 0; j < 16; ++j) ms[j] = (unsigned short)(m1[j] & 0x7FFu);
        uint4* op = (uint4*)(idx32 + ((pbase + row0 + r) * 32 + half * 16));
        op[0] = ((const uint4*)ms)[0];
        op[1] = ((const uint4*)ms)[1];
    }
}

// ---------------------------------------------------------------------------
// Fused rescore + gather + edge-MLP — WAVE-AUTONOMOUS, 4 ROWS PER WAVE.
// r1 counters showed 43% VALUBusy / 6% HBM (latency-bound); 2 rows/wave left
// too little independent work between the intra-wave fences. 4 rows/wave
// doubles in-flight gathers per phase and halves per-row fence + broadcast
// costs (wo loads serve 4 rows). All per-row arithmetic order-identical.
// Named scalars only (rule #20); launch_bounds caps VGPR at 128 (r3 lesson).
// ---------------------------------------------------------------------------
template <int D>
__global__ __launch_bounds__(256, 4) void rescore_gather_kernel(const float* __restrict__ feat,
                                                                const float* __restrict__ sq,
                                                                const unsigned short* __restrict__ idx32,
                                                                const float* __restrict__ P,
                                                                const float* __restrict__ Q,
                                                                const float* __restrict__ wo,
                                                                const float* __restrict__ bo,
                                                                float* __restrict__ outf) {
    __shared__ unsigned long long ScK[4][4][32];   // per-wave packed (d2,j) keys
    __shared__ int Li[4][4][KK];                   // per-wave selected indices
    __shared__ float Rl[4][4][HH];                 // per-wave relu-mean

    const int tid = threadIdx.x;
    const int wv = tid >> 6, ln = tid & 63;
    const int rw = ln >> 5, c = ln & 31;
    // batch->XCD pinning: each XCD's L2 sees only 4 batches' gather set
    const int xcd = blockIdx.x & 7;
    const int ii = blockIdx.x >> 3;            // 0..511
    const int batch = xcd + 8 * (ii >> 7);     // 4 batches per XCD
    const int rb = ii & 127;                   // 128 blocks x 16 rows = NN
    const long pbase = (long)batch * NN;
    const long pblk = pbase + (long)rb * 16;
    const int rA = wv * 4;                     // wave's first local row (of 16)

    // own candidates: lane (rw, c) owns cand c of rows rA+rw and rA+2+rw
    const int jown0 = (int)idx32[(pblk + rA + rw) * 32 + c];
    const int jown1 = (int)idx32[(pblk + rA + 2 + rw) * 32 + c];
    const float sqown0 = sq[pbase + jown0];
    const float sqown1 = sq[pbase + jown1];

    if constexpr (D == 64) {
        // quad-cooperative fp32 rescore: 4 lanes per cand, 64B granules
        const int cg = ln >> 2, e = ln & 3;
#pragma unroll
        for (int rr = 0; rr < 4; ++rr) {
            const float* rbase = feat + (pblk + rA + rr) * 64;
            const float4 rv0 = *(const float4*)(rbase + 0 * 16 + e * 4);
            const float4 rv1 = *(const float4*)(rbase + 1 * 16 + e * 4);
            const float4 rv2 = *(const float4*)(rbase + 2 * 16 + e * 4);
            const float4 rv3 = *(const float4*)(rbase + 3 * 16 + e * 4);
#pragma unroll
            for (int pp = 0; pp < 2; ++pp) {
                const int srcl = ((rr & 1) << 5) + pp * 16 + cg;
                const int jq = __shfl(rr < 2 ? jown0 : jown1, srcl);
                const float sqc = __shfl(rr < 2 ? sqown0 : sqown1, srcl);
                const float* cb = feat + (pbase + jq) * 64;
                const float4 cv0 = *(const float4*)(cb + 0 * 16 + e * 4);
                const float4 cv1 = *(const float4*)(cb + 1 * 16 + e * 4);
                const float4 cv2 = *(const float4*)(cb + 2 * 16 + e * 4);
                const float4 cv3 = *(const float4*)(cb + 3 * 16 + e * 4);
                float part = 0.f;
                part = fmaf(rv0.x, cv0.x, part); part = fmaf(rv0.y, cv0.y, part);
                part = fmaf(rv0.z, cv0.z, part); part = fmaf(rv0.w, cv0.w, part);
                part = fmaf(rv1.x, cv1.x, part); part = fmaf(rv1.y, cv1.y, part);
                part = fmaf(rv1.z, cv1.z, part); part = fmaf(rv1.w, cv1.w, part);
                part = fmaf(rv2.x, cv2.x, part); part = fmaf(rv2.y, cv2.y, part);
                part = fmaf(rv2.z, cv2.z, part); part = fmaf(rv2.w, cv2.w, part);
                part = fmaf(rv3.x, cv3.x, part); part = fmaf(rv3.y, cv3.y, part);
                part = fmaf(rv3.z, cv3.z, part); part = fmaf(rv3.w, cv3.w, part);
                part += __shfl_xor(part, 1);
                part += __shfl_xor(part, 2);
                if (e == 0)
                    ScK[wv][rr][pp * 16 + cg] =
                        pack64(fmaf(-2.0f, part, sqc), (unsigned int)jq);
            }
        }
    } else {
        // D==3: lane computes its own cands' exact d2 directly (2 rows)
        const float* rp0 = feat + (pblk + rA + rw) * 3;
        const float* rp1 = feat + (pblk + rA + 2 + rw) * 3;
        const float* cp0 = feat + (pbase + jown0) * 3;
        const float* cp1 = feat + (pbase + jown1) * 3;
        const float dot0 = fmaf(rp0[0], cp0[0], fmaf(rp0[1], cp0[1], rp0[2] * cp0[2]));
        const float dot1 = fmaf(rp1[0], cp1[0], fmaf(rp1[1], cp1[1], rp1[2] * cp1[2]));
        ScK[wv][rw][c] = pack64(fmaf(-2.0f, dot0, sqown0), (unsigned int)jown0);
        ScK[wv][2 + rw][c] = pack64(fmaf(-2.0f, dot1, sqown1), (unsigned int)jown1);
    }
    asm volatile("s_waitcnt lgkmcnt(0)" ::: "memory");
    __builtin_amdgcn_sched_barrier(0);

    // rank: exact lexicographic (d2, j) via single u64 compare, LDS broadcast
#pragma unroll
    for (int g = 0; g < 2; ++g) {
        const int rr = g * 2 + rw;
        const unsigned long long mykey = ScK[wv][rr][c];
        int rank = 0;
#pragma unroll
        for (int m = 0; m < 32; ++m)
            rank += (ScK[wv][rr][m] < mykey) ? 1 : 0;
        if (rank < KK) Li[wv][rr][rank] = (int)(mykey & 0x7FFu);
    }
    asm volatile("s_waitcnt lgkmcnt(0)" ::: "memory");
    __builtin_amdgcn_sched_barrier(0);

    // Phase 2: Q-gather + relu-mean; lane = h, 4 rows per wave
    const int h = ln;
    const long pA = pblk + rA;
    const float Pv0 = P[pA * HH + h];
    const float Pv1 = P[(pA + 1) * HH + h];
    const float Pv2 = P[(pA + 2) * HH + h];
    const float Pv3 = P[(pA + 3) * HH + h];
    float ac0 = 0.f, ac1 = 0.f, ac2 = 0.f, ac3 = 0.f;
#pragma unroll
    for (int kq = 0; kq < 4; ++kq) {
        const int4 a4 = *(const int4*)&Li[wv][0][kq * 4];   // uniform -> broadcast
        const int4 b4 = *(const int4*)&Li[wv][1][kq * 4];
        const int4 c4 = *(const int4*)&Li[wv][2][kq * 4];
        const int4 d4 = *(const int4*)&Li[wv][3][kq * 4];
        ac0 += fmaxf(Pv0 + Q[(pbase + a4.x) * HH + h], 0.f);
        ac0 += fmaxf(Pv0 + Q[(pbase + a4.y) * HH + h], 0.f);
        ac0 += fmaxf(Pv0 + Q[(pbase + a4.z) * HH + h], 0.f);
        ac0 += fmaxf(Pv0 + Q[(pbase + a4.w) * HH + h], 0.f);
        ac1 += fmaxf(Pv1 + Q[(pbase + b4.x) * HH + h], 0.f);
        ac1 += fmaxf(Pv1 + Q[(pbase + b4.y) * HH + h], 0.f);
        ac1 += fmaxf(Pv1 + Q[(pbase + b4.z) * HH + h], 0.f);
        ac1 += fmaxf(Pv1 + Q[(pbase + b4.w) * HH + h], 0.f);
        ac2 += fmaxf(Pv2 + Q[(pbase + c4.x) * HH + h], 0.f);
        ac2 += fmaxf(Pv2 + Q[(pbase + c4.y) * HH + h], 0.f);
        ac2 += fmaxf(Pv2 + Q[(pbase + c4.z) * HH + h], 0.f);
        ac2 += fmaxf(Pv2 + Q[(pbase + c4.w) * HH + h], 0.f);
        ac3 += fmaxf(Pv3 + Q[(pbase + d4.x) * HH + h], 0.f);
        ac3 += fmaxf(Pv3 + Q[(pbase + d4.y) * HH + h], 0.f);
        ac3 += fmaxf(Pv3 + Q[(pbase + d4.z) * HH + h], 0.f);
        ac3 += fmaxf(Pv3 + Q[(pbase + d4.w) * HH + h], 0.f);
    }
    Rl[wv][0][h] = ac0 * (1.f / KK);
    Rl[wv][1][h] = ac1 * (1.f / KK);
    Rl[wv][2][h] = ac2 * (1.f / KK);
    Rl[wv][3][h] = ac3 * (1.f / KK);
    asm volatile("s_waitcnt lgkmcnt(0)" ::: "memory");
    __builtin_amdgcn_sched_barrier(0);

    // wo matmul: 64 wo loads (L1-hot) serve 4 rows
    const float bh = bo[h];
    float o0 = bh, o1 = bh, o2 = bh, o3 = bh;
#pragma unroll
    for (int l4 = 0; l4 < 16; ++l4) {
        const float4 ra = *(const float4*)&Rl[wv][0][l4 * 4];   // uniform broadcast
        const float4 rb4 = *(const float4*)&Rl[wv][1][l4 * 4];
        const float4 rc4 = *(const float4*)&Rl[wv][2][l4 * 4];
        const float4 rd4 = *(const float4*)&Rl[wv][3][l4 * 4];
        const float* wp = wo + (l4 * 4) * HH + h;
        const float w0 = wp[0], w1 = wp[HH], w2 = wp[2 * HH], w3 = wp[3 * HH];
        o0 = fmaf(ra.x, w0, o0);  o1 = fmaf(rb4.x, w0, o1);
        o2 = fmaf(rc4.x, w0, o2); o3 = fmaf(rd4.x, w0, o3);
        o0 = fmaf(ra.y, w1, o0);  o1 = fmaf(rb4.y, w1, o1);
        o2 = fmaf(rc4.y, w1, o2); o3 = fmaf(rd4.y, w1, o3);
        o0 = fmaf(ra.z, w2, o0);  o1 = fmaf(rb4.z, w2, o1);
        o2 = fmaf(rc4.z, w2, o2); o3 = fmaf(rd4.z, w2, o3);
        o0 = fmaf(ra.w, w3, o0);  o1 = fmaf(rb4.w, w3, o1);
        o2 = fmaf(rc4.w, w3, o2); o3 = fmaf(rd4.w, w3, o3);
    }
    outf[pA * HH + h] = o0;
    outf[(pA + 1) * HH + h] = o1;
    outf[(pA + 2) * HH + h] = o2;
    outf[(pA + 3) * HH + h] = o3;
}

// ---------------------------------------------------------------------------
// pool partial: block = (batch, chunk of 8); sums 256 rows -> pp[batch][ch][64]
// ---------------------------------------------------------------------------
__global__ __launch_bounds__(256) void pool_partial_kernel(const float* __restrict__ feat,
                                                           float* __restrict__ pp) {
    __shared__ float part[4][HH];
    const int batch = blockIdx.x >> 3;
    const int chk = blockIdx.x & 7;
    const int tid = threadIdx.x;
    const int h = tid & 63;
    const int sub = tid >> 6;
    float s = 0.f;
    const float* fp = feat + ((long)batch * NN + chk * 256 + sub * 64) * HH + h;
    for (int n = 0; n < 64; ++n) s += fp[(long)n * HH];
    part[sub][h] = s;
    __syncthreads();
    if (tid < HH)
        pp[(batch * 8 + chk) * HH + h] = part[0][h] + part[1][h] + part[2][h] + part[3][h];
}

// ---------------------------------------------------------------------------
// head: g[b] = mean; out[b] = relu(g@fw1+fb1)@fw2+fb2. Block = batch.
// ---------------------------------------------------------------------------
__global__ __launch_bounds__(256) void head_kernel(const float* __restrict__ pp,
                                                   const float* __restrict__ fw1,
                                                   const float* __restrict__ fb1,
                                                   const float* __restrict__ fw2,
                                                   const float* __restrict__ fb2,
                                                   float* __restrict__ out) {
    __shared__ float g[HH];
    __shared__ float tl[HH];
    const int b = blockIdx.x;
    const int tid = threadIdx.x;
    if (tid < HH) {
        float s = 0.f;
#pragma unroll
        for (int c = 0; c < 8; ++c) s += pp[(b * 8 + c) * HH + tid];
        g[tid] = s * (1.f / NN);
    }
    __syncthreads();
    if (tid < HH) {
        float a = fb1[tid];
#pragma unroll
        for (int l = 0; l < HH; ++l) a = fmaf(g[l], fw1[l * HH + tid], a);
        tl[tid] = fmaxf(a, 0.f);
    }
    __syncthreads();
    if (tid < OUTC) {
        float o = fb2[tid];
#pragma unroll
        for (int l = 0; l < HH; ++l) o = fmaf(tl[l], fw2[l * OUTC + tid], o);
        out[(long)b * OUTC + tid] = o;
    }
}

// ---------------------------------------------------------------------------
extern "C" void kernel_launch(void* const* d_in, const int* in_sizes, int n_in,
                              void* d_out, int out_size, void* d_ws, size_t ws_size,
                              hipStream_t stream) {
    const float* x    = (const float*)d_in[0];
    const float* w1_0 = (const float*)d_in[1];
    const float* b1_0 = (const float*)d_in[2];
    const float* wo_0 = (const float*)d_in[3];
    const float* bo_0 = (const float*)d_in[4];
    const float* w1_1 = (const float*)d_in[5];
    const float* b1_1 = (const float*)d_in[6];
    const float* wo_1 = (const float*)d_in[7];
    const float* bo_1 = (const float*)d_in[8];
    const float* w1_2 = (const float*)d_in[9];
    const float* b1_2 = (const float*)d_in[10];
    const float* wo_2 = (const float*)d_in[11];
    const float* bo_2 = (const float*)d_in[12];
    const float* fw1  = (const float*)d_in[13];
    const float* fb1  = (const float*)d_in[14];
    const float* fw2  = (const float*)d_in[15];
    const float* fb2  = (const float*)d_in[16];
    float* out = (float*)d_out;

    // workspace layout (floats)
    float* featA = (float*)d_ws;
    float* featB = featA + (long)BN * HH;
    float* Pb    = featB + (long)BN * HH;
    float* Qb    = Pb + (long)BN * HH;
    float* sqb   = Qb + (long)BN * HH;
    unsigned short* idx32 = (unsigned short*)(sqb + BN);     // BN x 32 u16
    float* ppb   = (float*)(idx32 + (long)BN * 32);          // 32 x 8 x 64

    // bf16 feature mirrors alias the OPPOSITE feature buffer (consumed by the
    // filter before rescore_gather rewrites that buffer)
    __bf16* fbf1 = (__bf16*)featB;   // layer 1 (featB rewritten after filter)
    __bf16* fbf2 = (__bf16*)featA;   // layer 2 (featA rewritten after filter)

    // ---- layer 0 (D=3, exact fp32 kNN) ----
    prep3_kernel<<<BN / 4, 256, 0, stream>>>(x, w1_0, b1_0, sqb, Pb, Qb);
    knn3_filter_kernel<<<BB * 64, 256, 0, stream>>>(x, sqb, idx32);
    rescore_gather_kernel<3><<<BN / 16, 256, 0, stream>>>(x, sqb, idx32, Pb, Qb, wo_0, bo_0, featA);

    // ---- layer 1 (D=64) ----
    prep64_kernel<<<BN / 64, 256, 0, stream>>>(featA, w1_1, b1_1, fbf1, sqb, Pb, Qb);
    knn_filter_kernel<<<BB * 64, 256, 0, stream>>>(fbf1, sqb, idx32);
    rescore_gather_kernel<64><<<BN / 16, 256, 0, stream>>>(featA, sqb, idx32, Pb, Qb, wo_1, bo_1, featB);

    // ---- layer 2 (D=64) ----
    prep64_kernel<<<BN / 64, 256, 0, stream>>>(featB, w1_2, b1_2, fbf2, sqb, Pb, Qb);
    knn_filter_kernel<<<BB * 64, 256, 0, stream>>>(fbf2, sqb, idx32);
    rescore_gather_kernel<64><<<BN / 16, 256, 0, stream>>>(featB, sqb, idx32, Pb, Qb, wo_2, bo_2, featA);

    // ---- pool + head ----
    pool_partial_kernel<<<BB * 8, 256, 0, stream>>>(featA, ppb);
    head_kernel<<<BB, 256, 0, stream>>>(ppb, fw1, fb1, fw2, fb2, out);
}